// Round 1
// baseline (3666.465 us; speedup 1.0000x reference)
//
#include <hip/hip_runtime.h>
#include <hip/hip_bf16.h>
#include <cstddef>

#define TPB 256

// ---------------- workspace layout (float-element offsets) ----------------
// x0: [4,32,256,256]   @ 0          (8,388,608)
// x1: [4,64,128,128]   @ 8,388,608  (4,194,304)
// x2: [4,128,64,64]    @ 12,582,912 (2,097,152)
// x3: [4,256,128,128]  @ 33,554,432 (16,777,216)
// codes: [4,512,128,128] @ 0        (33,554,432)  -- reuses x0..x2 (dead)
// lab: [4,128,128] int @ 50,331,648 (65,536)
// cnt: [4,20] float    @ 50,397,184 (80)
static const size_t OFF_X0    = 0;
static const size_t OFF_X1    = 8388608;
static const size_t OFF_X2    = 12582912;
static const size_t OFF_X3    = 33554432;
static const size_t OFF_CODES = 0;
static const size_t OFF_LAB   = 50331648;
static const size_t OFF_CNT   = 50397184;

// ---------------- conv0: 3->32, 256x256, reflect pad 1 ----------------
// grid (256, 8, 4), block 256; 4 oc per thread
__global__ void conv0_kernel(const float* __restrict__ x, const float* __restrict__ w,
                             const float* __restrict__ bias, float* __restrict__ y) {
    int pix = blockIdx.x * TPB + threadIdx.x;      // 0..65535
    int i = pix >> 8, j = pix & 255;
    int ocg = blockIdx.y, b = blockIdx.z;
    const float* xb = x + (size_t)b * 3 * 65536;
    float acc[4];
#pragma unroll
    for (int o = 0; o < 4; ++o) acc[o] = bias[ocg * 4 + o];
    for (int c = 0; c < 3; ++c) {
        const float* xc = xb + c * 65536;
        const float* wc = w + ((ocg * 4) * 3 + c) * 9;
#pragma unroll
        for (int u = 0; u < 3; ++u) {
            int ii = i + u - 1; ii = ii < 0 ? 1 : (ii > 255 ? 254 : ii);
#pragma unroll
            for (int v = 0; v < 3; ++v) {
                int jj = j + v - 1; jj = jj < 0 ? 1 : (jj > 255 ? 254 : jj);
                float xv = xc[(ii << 8) + jj];
#pragma unroll
                for (int o = 0; o < 4; ++o) acc[o] += xv * wc[o * 27 + u * 3 + v];
            }
        }
    }
    float* yb = y + ((size_t)(b * 32 + ocg * 4)) * 65536;
#pragma unroll
    for (int o = 0; o < 4; ++o) yb[o * 65536 + pix] = acc[o];
}

// ---------------- instance norm + leaky relu (in place) ----------------
// grid (C, B), block 256
__global__ void in_lrelu_kernel(float* __restrict__ x, int HW) {
    size_t base = (size_t)(blockIdx.y * gridDim.x + blockIdx.x) * (size_t)HW;
    float* p = x + base;
    double s = 0.0, ss = 0.0;
    for (int k = threadIdx.x; k < HW; k += TPB) {
        float v = p[k];
        s += v; ss += (double)v * v;
    }
#pragma unroll
    for (int o = 32; o > 0; o >>= 1) {
        s  += __shfl_down(s, o);
        ss += __shfl_down(ss, o);
    }
    __shared__ double sh[2][4];
    int wv = threadIdx.x >> 6;
    if ((threadIdx.x & 63) == 0) { sh[0][wv] = s; sh[1][wv] = ss; }
    __syncthreads();
    if (threadIdx.x == 0) {
        double S  = sh[0][0] + sh[0][1] + sh[0][2] + sh[0][3];
        double SS = sh[1][0] + sh[1][1] + sh[1][2] + sh[1][3];
        double m = S / HW;
        double var = SS / HW - m * m;
        sh[0][0] = m;
        sh[1][0] = 1.0 / sqrt(var + 1e-5);
    }
    __syncthreads();
    float m = (float)sh[0][0], inv = (float)sh[1][0];
    for (int k = threadIdx.x; k < HW; k += TPB) {
        float v = (p[k] - m) * inv;
        p[k] = v >= 0.0f ? v : 0.2f * v;
    }
}

// ---------------- strided conv (stride 2, zero pad 1) ----------------
// grid (OH*OW/256, OC/4, B), block 256; 4 oc per thread
template<int IC, int IH, int IW, int OH, int OW>
__global__ void conv_s2_kernel(const float* __restrict__ x, const float* __restrict__ w,
                               const float* __restrict__ bias, float* __restrict__ y, int OC) {
    int pix = blockIdx.x * TPB + threadIdx.x;
    int i = pix / OW, j = pix % OW;
    int ocg = blockIdx.y, b = blockIdx.z;
    const float* xb = x + (size_t)b * IC * IH * IW;
    float acc[4];
#pragma unroll
    for (int o = 0; o < 4; ++o) acc[o] = bias[ocg * 4 + o];
    for (int c = 0; c < IC; ++c) {
        const float* xc = xb + c * IH * IW;
        const float* wc = w + ((ocg * 4) * IC + c) * 9;
#pragma unroll
        for (int u = 0; u < 3; ++u) {
            int ii = 2 * i + u - 1;
            if (ii < 0 || ii >= IH) continue;
#pragma unroll
            for (int v = 0; v < 3; ++v) {
                int jj = 2 * j + v - 1;
                if (jj < 0 || jj >= IW) continue;
                float xv = xc[ii * IW + jj];
#pragma unroll
                for (int o = 0; o < 4; ++o) acc[o] += xv * wc[o * IC * 9 + u * 3 + v];
            }
        }
    }
    float* yb = y + ((size_t)(b * OC) + ocg * 4) * (size_t)(OH * OW);
#pragma unroll
    for (int o = 0; o < 4; ++o) yb[o * OH * OW + pix] = acc[o];
}

// ---------------- transposed conv 128->256 (lhs-dilated), parity-split ----------------
// x: [B,128,64,64], w: [256,128,3,3] (OIHW), y: [B,256,128,128]
// grid (16, 64, 8) where z = b*2 + pi; block 256. Each thread: one (a,bb) cell,
// both column parities, 4 oc.
__global__ void convt_kernel(const float* __restrict__ x, const float* __restrict__ w,
                             const float* __restrict__ bias, float* __restrict__ y) {
    int pi = blockIdx.z & 1, b = blockIdx.z >> 1;
    int cell = blockIdx.x * TPB + threadIdx.x;   // 0..4095
    int a = cell >> 6, bb = cell & 63;
    int ocg = blockIdx.y;
    const float* xb = x + (size_t)b * 128 * 4096;
    const float* wg = w + (size_t)(ocg * 4) * 128 * 9;
    float acc0[4], acc1[4];
#pragma unroll
    for (int o = 0; o < 4; ++o) { float bv = bias[ocg * 4 + o]; acc0[o] = bv; acc1[o] = bv; }
    bool hasC1 = (bb < 63);
    bool hasR1 = (a < 63);
    if (pi == 0) {
        // even output row: only u=1 taps
        for (int c = 0; c < 128; ++c) {
            const float* xc = xb + c * 4096 + a * 64;
            float x0 = xc[bb];
            float x1 = hasC1 ? xc[bb + 1] : 0.0f;
            const float* wc = wg + c * 9;
#pragma unroll
            for (int o = 0; o < 4; ++o) {
                const float* wo = wc + o * 128 * 9;
                acc0[o] += x0 * wo[4];                    // (1,1)
                acc1[o] += x0 * wo[3] + x1 * wo[5];       // (1,0),(1,2)
            }
        }
    } else {
        // odd output row: u in {0,2}
        for (int c = 0; c < 128; ++c) {
            const float* xc = xb + c * 4096;
            float x00 = xc[a * 64 + bb];
            float x01 = hasC1 ? xc[a * 64 + bb + 1] : 0.0f;
            float x10 = hasR1 ? xc[(a + 1) * 64 + bb] : 0.0f;
            float x11 = (hasR1 && hasC1) ? xc[(a + 1) * 64 + bb + 1] : 0.0f;
            const float* wc = wg + c * 9;
#pragma unroll
            for (int o = 0; o < 4; ++o) {
                const float* wo = wc + o * 128 * 9;
                acc0[o] += x00 * wo[1] + x10 * wo[7];                                  // (0,1),(2,1)
                acc1[o] += x00 * wo[0] + x01 * wo[2] + x10 * wo[6] + x11 * wo[8];      // (0,0),(0,2),(2,0),(2,2)
            }
        }
    }
    float* yb = y + ((size_t)(b * 256 + ocg * 4)) * 16384 + (2 * a + pi) * 128 + 2 * bb;
#pragma unroll
    for (int o = 0; o < 4; ++o) {
        float2 v = make_float2(acc0[o], acc1[o]);
        *(float2*)&yb[o * 16384] = v;
    }
}

// ---------------- conv3: 256->512, 128x128, reflect pad 1, + bias + tanh ----------------
// grid (64 ocg, 16 tiles, 4 b), block 256. 32x32 output tile; 8-ic LDS chunks;
// each thread: 4 consecutive px * 8 oc. Weights via wave-uniform (scalar) loads.
#define C3_CHUNK 8
__global__ __launch_bounds__(256) void conv3_kernel(const float* __restrict__ x,
                                                    const float* __restrict__ w,
                                                    const float* __restrict__ bias,
                                                    float* __restrict__ y) {
    __shared__ float tile[C3_CHUNK][34][36];     // row padded to 36 for 16B-aligned b128 reads
    int ocg = blockIdx.x, tidx = blockIdx.y, b = blockIdx.z;
    int trow = (tidx >> 2) << 5, tcol = (tidx & 3) << 5;
    int tid = threadIdx.x;
    int ty = tid >> 3, tx0 = (tid & 7) << 2;
    const float* xb = x + (size_t)b * 256 * 16384;
    const float* wg = w + (size_t)ocg * 8 * 256 * 9;
    float acc[8][4];
#pragma unroll
    for (int o = 0; o < 8; ++o) {
        float bv = bias[ocg * 8 + o];
#pragma unroll
        for (int k = 0; k < 4; ++k) acc[o][k] = bv;
    }
    for (int cc0 = 0; cc0 < 256; cc0 += C3_CHUNK) {
        __syncthreads();
        for (int ci = 0; ci < C3_CHUNK; ++ci) {
            const float* xc = xb + (size_t)(cc0 + ci) * 16384;
            for (int k = tid; k < 34 * 34; k += TPB) {
                int rr = k / 34, cn = k - rr * 34;
                int gi = trow + rr - 1; gi = gi < 0 ? 1 : (gi > 127 ? 126 : gi);
                int gj = tcol + cn - 1; gj = gj < 0 ? 1 : (gj > 127 ? 126 : gj);
                tile[ci][rr][cn] = xc[(gi << 7) + gj];
            }
        }
        __syncthreads();
#pragma unroll 2
        for (int ci = 0; ci < C3_CHUNK; ++ci) {
            float xr[3][6];
#pragma unroll
            for (int u = 0; u < 3; ++u) {
                const float* rp = &tile[ci][ty + u][tx0];
#pragma unroll
                for (int v6 = 0; v6 < 6; ++v6) xr[u][v6] = rp[v6];
            }
            const float* wc = wg + (size_t)(cc0 + ci) * 9;
#pragma unroll
            for (int u = 0; u < 3; ++u)
#pragma unroll
                for (int v = 0; v < 3; ++v) {
#pragma unroll
                    for (int o = 0; o < 8; ++o) {
                        float wv = wc[o * 256 * 9 + u * 3 + v];
#pragma unroll
                        for (int k = 0; k < 4; ++k) acc[o][k] += xr[u][v + k] * wv;
                    }
                }
        }
    }
    float* yb = y + ((size_t)(b * 512 + ocg * 8)) * 16384 + (trow + ty) * 128 + tcol + tx0;
#pragma unroll
    for (int o = 0; o < 8; ++o) {
        float4 v = make_float4(tanhf(acc[o][0]), tanhf(acc[o][1]),
                               tanhf(acc[o][2]), tanhf(acc[o][3]));
        *(float4*)&yb[o * 16384] = v;
    }
}

// ---------------- labels + counts ----------------
// grid (64, 4), block 256. lab[b,i,j] in [0,20) or -1 if foreground.
__global__ void label_kernel(const float* __restrict__ seg, const float* __restrict__ fg,
                             int* __restrict__ lab, float* __restrict__ counts) {
    int b = blockIdx.y;
    int pix = blockIdx.x * TPB + threadIdx.x;    // 0..16383 over 128x128
    int i = pix >> 7, j = pix & 127;
    int src = ((i * 2) << 8) + (j * 2);          // nearest: floor(i * 2)
    const float* fgb = fg + (size_t)b * 65536;
    int l = -1;
    if (fgb[src] == 0.0f) {
        const float* sb = seg + (size_t)b * 20 * 65536;
        for (int s = 0; s < 20; ++s)
            if (sb[(size_t)s * 65536 + src] != 0.0f) { l = s; break; }
    }
    lab[b * 16384 + pix] = l;
    __shared__ int bins[20];
    if (threadIdx.x < 20) bins[threadIdx.x] = 0;
    __syncthreads();
    if (l >= 0) atomicAdd(&bins[l], 1);
    __syncthreads();
    if (threadIdx.x < 20 && bins[threadIdx.x] > 0)
        atomicAdd(&counts[b * 20 + threadIdx.x], (float)bins[threadIdx.x]);
}

// ---------------- segment sums + divide ----------------
// grid (512, 4), block 256. One block per (b, f channel).
__global__ void segsum_kernel(const float* __restrict__ codes, const int* __restrict__ lab,
                              const float* __restrict__ counts, float* __restrict__ out) {
    int f = blockIdx.x, b = blockIdx.y;
    const float* cb = codes + ((size_t)(b * 512 + f)) * 16384;
    const int* lb = lab + b * 16384;
    __shared__ float bins[4][20];
    for (int k = threadIdx.x; k < 80; k += TPB) bins[k / 20][k % 20] = 0.0f;
    __syncthreads();
    int wv = threadIdx.x >> 6;
    for (int p = threadIdx.x; p < 16384; p += TPB) {
        float v = cb[p];
        int l = lb[p];
        if (l >= 0) atomicAdd(&bins[wv][l], v);
    }
    __syncthreads();
    if (threadIdx.x < 20) {
        int s = threadIdx.x;
        float t = bins[0][s] + bins[1][s] + bins[2][s] + bins[3][s];
        float c = counts[b * 20 + s];
        out[((size_t)(b * 20 + s)) * 512 + f] = c > 0.0f ? t / c : 0.0f;
    }
}

// ---------------- launch ----------------
extern "C" void kernel_launch(void* const* d_in, const int* in_sizes, int n_in,
                              void* d_out, int out_size, void* d_ws, size_t ws_size,
                              hipStream_t stream) {
    const float* input = (const float*)d_in[0];
    const float* segmap = (const float*)d_in[1];
    const float* fg = (const float*)d_in[2];
    const float* w0 = (const float*)d_in[3];  const float* b0 = (const float*)d_in[4];
    const float* w1 = (const float*)d_in[5];  const float* b1 = (const float*)d_in[6];
    const float* w2 = (const float*)d_in[7];  const float* b2 = (const float*)d_in[8];
    const float* wt = (const float*)d_in[9];  const float* bt = (const float*)d_in[10];
    const float* w3 = (const float*)d_in[11]; const float* b3 = (const float*)d_in[12];

    float* ws = (float*)d_ws;
    float* x0 = ws + OFF_X0;
    float* x1 = ws + OFF_X1;
    float* x2 = ws + OFF_X2;
    float* x3 = ws + OFF_X3;
    float* codes = ws + OFF_CODES;
    int*   lab = (int*)(ws + OFF_LAB);
    float* cnt = ws + OFF_CNT;
    float* out = (float*)d_out;

    // stage 0: conv0 + IN + lrelu    -> x0 [4,32,256,256]
    conv0_kernel<<<dim3(256, 8, 4), TPB, 0, stream>>>(input, w0, b0, x0);
    in_lrelu_kernel<<<dim3(32, 4), TPB, 0, stream>>>(x0, 65536);
    // stage 1: s2 conv 32->64 + IN + lrelu -> x1 [4,64,128,128]
    conv_s2_kernel<32, 256, 256, 128, 128><<<dim3(64, 16, 4), TPB, 0, stream>>>(x0, w1, b1, x1, 64);
    in_lrelu_kernel<<<dim3(64, 4), TPB, 0, stream>>>(x1, 16384);
    // stage 2: s2 conv 64->128 + IN + lrelu -> x2 [4,128,64,64]
    conv_s2_kernel<64, 128, 128, 64, 64><<<dim3(16, 32, 4), TPB, 0, stream>>>(x1, w2, b2, x2, 128);
    in_lrelu_kernel<<<dim3(128, 4), TPB, 0, stream>>>(x2, 4096);
    // stage 3: convT 128->256 + IN + lrelu -> x3 [4,256,128,128]
    convt_kernel<<<dim3(16, 64, 8), TPB, 0, stream>>>(x2, wt, bt, x3);
    in_lrelu_kernel<<<dim3(256, 4), TPB, 0, stream>>>(x3, 16384);
    // stage 4: conv3 256->512 + tanh -> codes [4,512,128,128]
    conv3_kernel<<<dim3(64, 16, 4), TPB, 0, stream>>>(x3, w3, b3, codes);
    // stage 5: segment mean
    hipMemsetAsync(cnt, 0, 80 * sizeof(float), stream);
    label_kernel<<<dim3(64, 4), TPB, 0, stream>>>(segmap, fg, lab, cnt);
    segsum_kernel<<<dim3(512, 4), TPB, 0, stream>>>(codes, lab, cnt, out);
}

// Round 2
// 1218.946 us; speedup vs baseline: 3.0079x; 3.0079x over previous
//
#include <hip/hip_runtime.h>
#include <hip/hip_bf16.h>
#include <cstddef>

#define TPB 256

typedef float f32x4_t __attribute__((ext_vector_type(4)));
typedef __bf16 bf16x8_t __attribute__((ext_vector_type(8)));
typedef unsigned short u16x8_t __attribute__((ext_vector_type(8)));

// ---------------- workspace layout (float-element offsets) ----------------
// x0:  [4,32,256,256]        @ 0           (8,388,608)
// x1:  [4,64,128,128]        @ 8,388,608   (4,194,304)
// x2:  [4,128,64,64]         @ 12,582,912  (2,097,152)
// x3:  [4,256,128,128]       @ 14,680,064  (16,777,216) ends 31,457,280
// x3h: [4,128,128,256] bf16  @ 0           (8,388,608 float slots) -- x0 dead
// codes:[4,512,128,128]      @ 8,388,608   (33,554,432) ends 41,943,040 -- x1,x2,x3 dead
// lab: [4,128,128] int       @ 41,943,040  (65,536)
// cnt: [4,20] float          @ 42,008,576  (80)
// wph: [9,512,256] bf16      @ 42,008,704  (589,824 slots)
// wpl: [9,512,256] bf16      @ 42,598,528  (589,824 slots) ends 43,188,352 (~173MB)
static const size_t OFF_X0    = 0;
static const size_t OFF_X1    = 8388608;
static const size_t OFF_X2    = 12582912;
static const size_t OFF_X3    = 14680064;
static const size_t OFF_X3H   = 0;
static const size_t OFF_CODES = 8388608;
static const size_t OFF_LAB   = 41943040;
static const size_t OFF_CNT   = 42008576;
static const size_t OFF_WPH   = 42008704;
static const size_t OFF_WPL   = 42598528;

__device__ __forceinline__ unsigned short f2bf(float f) {
    unsigned int u = __float_as_uint(f);
    unsigned int r = u + 0x7FFFu + ((u >> 16) & 1u);   // RNE (finite inputs)
    return (unsigned short)(r >> 16);
}
__device__ __forceinline__ float bf2f(unsigned short h) {
    return __uint_as_float(((unsigned int)h) << 16);
}

// ---------------- conv0: 3->32, 256x256, reflect pad 1 ----------------
__global__ void conv0_kernel(const float* __restrict__ x, const float* __restrict__ w,
                             const float* __restrict__ bias, float* __restrict__ y) {
    int pix = blockIdx.x * TPB + threadIdx.x;
    int i = pix >> 8, j = pix & 255;
    int ocg = blockIdx.y, b = blockIdx.z;
    const float* xb = x + (size_t)b * 3 * 65536;
    float acc[4];
#pragma unroll
    for (int o = 0; o < 4; ++o) acc[o] = bias[ocg * 4 + o];
    for (int c = 0; c < 3; ++c) {
        const float* xc = xb + c * 65536;
        const float* wc = w + ((ocg * 4) * 3 + c) * 9;
#pragma unroll
        for (int u = 0; u < 3; ++u) {
            int ii = i + u - 1; ii = ii < 0 ? 1 : (ii > 255 ? 254 : ii);
#pragma unroll
            for (int v = 0; v < 3; ++v) {
                int jj = j + v - 1; jj = jj < 0 ? 1 : (jj > 255 ? 254 : jj);
                float xv = xc[(ii << 8) + jj];
#pragma unroll
                for (int o = 0; o < 4; ++o) acc[o] += xv * wc[o * 27 + u * 3 + v];
            }
        }
    }
    float* yb = y + ((size_t)(b * 32 + ocg * 4)) * 65536;
#pragma unroll
    for (int o = 0; o < 4; ++o) yb[o * 65536 + pix] = acc[o];
}

// ---------------- instance norm + leaky relu (in place) ----------------
__global__ void in_lrelu_kernel(float* __restrict__ x, int HW) {
    size_t base = (size_t)(blockIdx.y * gridDim.x + blockIdx.x) * (size_t)HW;
    float* p = x + base;
    double s = 0.0, ss = 0.0;
    for (int k = threadIdx.x; k < HW; k += TPB) {
        float v = p[k];
        s += v; ss += (double)v * v;
    }
#pragma unroll
    for (int o = 32; o > 0; o >>= 1) {
        s  += __shfl_down(s, o);
        ss += __shfl_down(ss, o);
    }
    __shared__ double sh[2][4];
    int wv = threadIdx.x >> 6;
    if ((threadIdx.x & 63) == 0) { sh[0][wv] = s; sh[1][wv] = ss; }
    __syncthreads();
    if (threadIdx.x == 0) {
        double S  = sh[0][0] + sh[0][1] + sh[0][2] + sh[0][3];
        double SS = sh[1][0] + sh[1][1] + sh[1][2] + sh[1][3];
        double m = S / HW;
        double var = SS / HW - m * m;
        sh[0][0] = m;
        sh[1][0] = 1.0 / sqrt(var + 1e-5);
    }
    __syncthreads();
    float m = (float)sh[0][0], inv = (float)sh[1][0];
    for (int k = threadIdx.x; k < HW; k += TPB) {
        float v = (p[k] - m) * inv;
        p[k] = v >= 0.0f ? v : 0.2f * v;
    }
}

// ---------------- strided conv (stride 2, zero pad 1) ----------------
template<int IC, int IH, int IW, int OH, int OW>
__global__ void conv_s2_kernel(const float* __restrict__ x, const float* __restrict__ w,
                               const float* __restrict__ bias, float* __restrict__ y, int OC) {
    int pix = blockIdx.x * TPB + threadIdx.x;
    int i = pix / OW, j = pix % OW;
    int ocg = blockIdx.y, b = blockIdx.z;
    const float* xb = x + (size_t)b * IC * IH * IW;
    float acc[4];
#pragma unroll
    for (int o = 0; o < 4; ++o) acc[o] = bias[ocg * 4 + o];
    for (int c = 0; c < IC; ++c) {
        const float* xc = xb + c * IH * IW;
        const float* wc = w + ((ocg * 4) * IC + c) * 9;
#pragma unroll
        for (int u = 0; u < 3; ++u) {
            int ii = 2 * i + u - 1;
            if (ii < 0 || ii >= IH) continue;
#pragma unroll
            for (int v = 0; v < 3; ++v) {
                int jj = 2 * j + v - 1;
                if (jj < 0 || jj >= IW) continue;
                float xv = xc[ii * IW + jj];
#pragma unroll
                for (int o = 0; o < 4; ++o) acc[o] += xv * wc[o * IC * 9 + u * 3 + v];
            }
        }
    }
    float* yb = y + ((size_t)(b * OC) + ocg * 4) * (size_t)(OH * OW);
#pragma unroll
    for (int o = 0; o < 4; ++o) yb[o * OH * OW + pix] = acc[o];
}

// ---------------- transposed conv 128->256, parity-split ----------------
__global__ void convt_kernel(const float* __restrict__ x, const float* __restrict__ w,
                             const float* __restrict__ bias, float* __restrict__ y) {
    int pi = blockIdx.z & 1, b = blockIdx.z >> 1;
    int cell = blockIdx.x * TPB + threadIdx.x;
    int a = cell >> 6, bb = cell & 63;
    int ocg = blockIdx.y;
    const float* xb = x + (size_t)b * 128 * 4096;
    const float* wg = w + (size_t)(ocg * 4) * 128 * 9;
    float acc0[4], acc1[4];
#pragma unroll
    for (int o = 0; o < 4; ++o) { float bv = bias[ocg * 4 + o]; acc0[o] = bv; acc1[o] = bv; }
    bool hasC1 = (bb < 63);
    bool hasR1 = (a < 63);
    if (pi == 0) {
        for (int c = 0; c < 128; ++c) {
            const float* xc = xb + c * 4096 + a * 64;
            float x0 = xc[bb];
            float x1 = hasC1 ? xc[bb + 1] : 0.0f;
            const float* wc = wg + c * 9;
#pragma unroll
            for (int o = 0; o < 4; ++o) {
                const float* wo = wc + o * 128 * 9;
                acc0[o] += x0 * wo[4];
                acc1[o] += x0 * wo[3] + x1 * wo[5];
            }
        }
    } else {
        for (int c = 0; c < 128; ++c) {
            const float* xc = xb + c * 4096;
            float x00 = xc[a * 64 + bb];
            float x01 = hasC1 ? xc[a * 64 + bb + 1] : 0.0f;
            float x10 = hasR1 ? xc[(a + 1) * 64 + bb] : 0.0f;
            float x11 = (hasR1 && hasC1) ? xc[(a + 1) * 64 + bb + 1] : 0.0f;
            const float* wc = wg + c * 9;
#pragma unroll
            for (int o = 0; o < 4; ++o) {
                const float* wo = wc + o * 128 * 9;
                acc0[o] += x00 * wo[1] + x10 * wo[7];
                acc1[o] += x00 * wo[0] + x01 * wo[2] + x10 * wo[6] + x11 * wo[8];
            }
        }
    }
    float* yb = y + ((size_t)(b * 256 + ocg * 4)) * 16384 + (2 * a + pi) * 128 + 2 * bb;
#pragma unroll
    for (int o = 0; o < 4; ++o) {
        float2 v = make_float2(acc0[o], acc1[o]);
        *(float2*)&yb[o * 16384] = v;
    }
}

// ---------------- transpose+convert: x3 [b,c,h,w] f32 -> x3h [b,h,w,c] bf16 ----------------
// grid (8 = 2 wtiles * 4 ctiles, 128 h, 4 b), block 256
__global__ void transpose_bf16_kernel(const float* __restrict__ x3, unsigned short* __restrict__ x3h) {
    __shared__ __align__(16) unsigned short tile[64][264];   // [px][c], row stride 528B (16B aligned)
    int wt = blockIdx.x & 1, ct = blockIdx.x >> 1;
    int h = blockIdx.y, b = blockIdx.z;
    int c0 = ct * 64, w0 = wt * 64;
    int t = threadIdx.x;
    int px = t & 63, cr = t >> 6;
    const float* src = x3 + ((size_t)(b * 256 + c0)) * 16384 + h * 128 + w0;
#pragma unroll
    for (int it = 0; it < 16; ++it) {
        int c = cr + 4 * it;
        tile[px][c] = f2bf(src[(size_t)c * 16384 + px]);
    }
    __syncthreads();
    unsigned short* dst = x3h + (((size_t)(b * 128 + h) * 128) + w0) * 256 + c0;
#pragma unroll
    for (int it = 0; it < 2; ++it) {
        int flat = (it << 8) + t;
        int p2 = flat >> 3, c8 = (flat & 7) << 3;
        u16x8_t vv = *(const u16x8_t*)&tile[p2][c8];
        *(u16x8_t*)&dst[(size_t)p2 * 256 + c8] = vv;
    }
}

// ---------------- weight pack: w3 [512,256,3,3] -> wph/wpl [9,512,256] bf16 (hi/lo split) ----------------
__global__ void packw_kernel(const float* __restrict__ w3, unsigned short* __restrict__ wph,
                             unsigned short* __restrict__ wpl) {
    int id = blockIdx.x * TPB + threadIdx.x;       // ((t*512 + o)*256 + c)
    if (id >= 9 * 512 * 256) return;
    int c = id & 255; int to = id >> 8; int o = to & 511; int tt = to >> 9;
    float v = w3[((size_t)o * 256 + c) * 9 + tt];
    unsigned short hb = f2bf(v);
    unsigned short lb = f2bf(v - bf2f(hb));
    wph[id] = hb;
    wpl[id] = lb;
}

// ---------------- conv3: 256->512 @128x128, reflect pad, bias+tanh, bf16 MFMA ----------------
// Implicit GEMM: M=oc, N=pixels, K=ic (32-chunks) x 9 taps. Split-A (hi/lo weights).
// Block: 512 thr / 8 waves. Output per block: 64 oc x (8 rows x 64 cols). Wave w -> row w.
// LDS: W[9 taps][2 hi/lo][64 oc][32 ic] bf16 (73,728B)  +  X[10 rows][66 cols][32 ic] (42,240B)
// Both layouts give uniform 8-lanes-per-4-bank-group on ds_read_b128 (conflict-free floor).
__global__ __launch_bounds__(512, 2) void conv3_mfma_kernel(
    const unsigned short* __restrict__ xh,   // [4][128][128][256] bf16
    const unsigned short* __restrict__ wh,   // [9][512][256] bf16
    const unsigned short* __restrict__ wl,   // [9][512][256] bf16
    const float* __restrict__ bias, float* __restrict__ y) {
    __shared__ __align__(16) unsigned short ldsW[9][2][64][32];
    __shared__ __align__(16) unsigned short ldsX[10][66][32];
    int ocg = blockIdx.x;                       // 0..7
    int tr = blockIdx.y >> 1, tc = blockIdx.y & 1;
    int b = blockIdx.z;
    int tid = threadIdx.x;
    int l = tid & 63, w = tid >> 6;             // lane, wave(=output row)
    int px = l & 15, g = l >> 4;
    int r0 = tr * 8, c0 = tc * 64;

    f32x4_t acc[4][4];
#pragma unroll
    for (int m = 0; m < 4; ++m)
#pragma unroll
        for (int r = 0; r < 4; ++r) {
            float bv = bias[ocg * 64 + 16 * m + 4 * g + r];
#pragma unroll
            for (int j = 0; j < 4; ++j) acc[m][j][r] = bv;
        }

    const unsigned short* xbase = xh + (size_t)b * (128 * 128 * 256);
    unsigned short* ldsWf = &ldsW[0][0][0][0];
    unsigned short* ldsXf = &ldsX[0][0][0];

    for (int cc = 0; cc < 256; cc += 32) {
        __syncthreads();                         // previous chunk's readers done
        // ---- stage W: 9*2*64*32 = 36864 elems = 4608 x 16B chunks, 9/thread ----
#pragma unroll
        for (int k = 0; k < 9; ++k) {
            int c16 = (k << 9) + tid;
            int ic8 = (c16 & 3) << 3;
            int hto = c16 >> 2;                  // [t][h][o]
            int o = hto & 63;
            int th = hto >> 6;
            int h = th & 1, ttap = th >> 1;
            const unsigned short* srcp = (h ? wl : wh) +
                (((size_t)ttap * 512 + ocg * 64 + o) << 8) + cc + ic8;
            u16x8_t vv = *(const u16x8_t*)srcp;
            *(u16x8_t*)(ldsWf + (c16 << 3)) = vv;
        }
        // ---- stage X: 10*66*32 = 21120 elems = 2640 x 16B chunks ----
#pragma unroll
        for (int k = 0; k < 6; ++k) {
            int c16 = (k << 9) + tid;
            if (c16 < 2640) {
                int ic8 = (c16 & 3) << 3;
                int rc = c16 >> 2;               // 0..659
                int row = (rc * 993) >> 16;      // rc / 66 (valid for rc < 726)
                int col = rc - row * 66;
                int gi = r0 + row - 1; gi = gi < 0 ? 1 : (gi > 127 ? 126 : gi);
                int gj = c0 + col - 1; gj = gj < 0 ? 1 : (gj > 127 ? 126 : gj);
                const unsigned short* srcp = xbase + (((size_t)(gi << 7) + gj) << 8) + cc + ic8;
                u16x8_t vv = *(const u16x8_t*)srcp;
                *(u16x8_t*)(ldsXf + (c16 << 3)) = vv;
            }
        }
        __syncthreads();
        // ---- compute: 9 taps x (4 m-frags hi/lo + 4 n-frags) ----
#pragma unroll
        for (int u = 0; u < 3; ++u) {
#pragma unroll
            for (int v = 0; v < 3; ++v) {
                int t3 = 3 * u + v;
                bf16x8_t Ah[4], Al[4], Bf[4];
#pragma unroll
                for (int m = 0; m < 4; ++m) {
                    Ah[m] = *(const bf16x8_t*)&ldsW[t3][0][16 * m + px][g << 3];
                    Al[m] = *(const bf16x8_t*)&ldsW[t3][1][16 * m + px][g << 3];
                }
#pragma unroll
                for (int j = 0; j < 4; ++j)
                    Bf[j] = *(const bf16x8_t*)&ldsX[w + u][v + 16 * j + px][g << 3];
#pragma unroll
                for (int m = 0; m < 4; ++m)
#pragma unroll
                    for (int j = 0; j < 4; ++j) {
                        acc[m][j] = __builtin_amdgcn_mfma_f32_16x16x32_bf16(Ah[m], Bf[j], acc[m][j], 0, 0, 0);
                        acc[m][j] = __builtin_amdgcn_mfma_f32_16x16x32_bf16(Al[m], Bf[j], acc[m][j], 0, 0, 0);
                    }
            }
        }
    }
    // ---- epilogue: C/D map col=lane&15 (px), row=4*(lane>>4)+reg (oc) ----
    float* yb = y + ((size_t)(b * 512 + ocg * 64)) * 16384;
    int row = r0 + w;
#pragma unroll
    for (int m = 0; m < 4; ++m)
#pragma unroll
        for (int r = 0; r < 4; ++r) {
            int oc = 16 * m + 4 * g + r;
            float* yp = yb + (size_t)oc * 16384 + (row << 7) + c0;
#pragma unroll
            for (int j = 0; j < 4; ++j)
                yp[16 * j + px] = tanhf(acc[m][j][r]);
        }
}

// ---------------- labels + counts ----------------
__global__ void label_kernel(const float* __restrict__ seg, const float* __restrict__ fg,
                             int* __restrict__ lab, float* __restrict__ counts) {
    int b = blockIdx.y;
    int pix = blockIdx.x * TPB + threadIdx.x;
    int i = pix >> 7, j = pix & 127;
    int src = ((i * 2) << 8) + (j * 2);
    const float* fgb = fg + (size_t)b * 65536;
    int l = -1;
    if (fgb[src] == 0.0f) {
        const float* sb = seg + (size_t)b * 20 * 65536;
        for (int s = 0; s < 20; ++s)
            if (sb[(size_t)s * 65536 + src] != 0.0f) { l = s; break; }
    }
    lab[b * 16384 + pix] = l;
    __shared__ int bins[20];
    if (threadIdx.x < 20) bins[threadIdx.x] = 0;
    __syncthreads();
    if (l >= 0) atomicAdd(&bins[l], 1);
    __syncthreads();
    if (threadIdx.x < 20 && bins[threadIdx.x] > 0)
        atomicAdd(&counts[b * 20 + threadIdx.x], (float)bins[threadIdx.x]);
}

// ---------------- segment sums + divide ----------------
__global__ void segsum_kernel(const float* __restrict__ codes, const int* __restrict__ lab,
                              const float* __restrict__ counts, float* __restrict__ out) {
    int f = blockIdx.x, b = blockIdx.y;
    const float* cb = codes + ((size_t)(b * 512 + f)) * 16384;
    const int* lb = lab + b * 16384;
    __shared__ float bins[4][20];
    for (int k = threadIdx.x; k < 80; k += TPB) bins[k / 20][k % 20] = 0.0f;
    __syncthreads();
    int wv = threadIdx.x >> 6;
    for (int p = threadIdx.x; p < 16384; p += TPB) {
        float v = cb[p];
        int l = lb[p];
        if (l >= 0) atomicAdd(&bins[wv][l], v);
    }
    __syncthreads();
    if (threadIdx.x < 20) {
        int s = threadIdx.x;
        float t = bins[0][s] + bins[1][s] + bins[2][s] + bins[3][s];
        float c = counts[b * 20 + s];
        out[((size_t)(b * 20 + s)) * 512 + f] = c > 0.0f ? t / c : 0.0f;
    }
}

// ---------------- launch ----------------
extern "C" void kernel_launch(void* const* d_in, const int* in_sizes, int n_in,
                              void* d_out, int out_size, void* d_ws, size_t ws_size,
                              hipStream_t stream) {
    const float* input = (const float*)d_in[0];
    const float* segmap = (const float*)d_in[1];
    const float* fg = (const float*)d_in[2];
    const float* w0 = (const float*)d_in[3];  const float* b0 = (const float*)d_in[4];
    const float* w1 = (const float*)d_in[5];  const float* b1 = (const float*)d_in[6];
    const float* w2 = (const float*)d_in[7];  const float* b2 = (const float*)d_in[8];
    const float* wt = (const float*)d_in[9];  const float* bt = (const float*)d_in[10];
    const float* w3 = (const float*)d_in[11]; const float* b3 = (const float*)d_in[12];

    float* ws = (float*)d_ws;
    float* x0 = ws + OFF_X0;
    float* x1 = ws + OFF_X1;
    float* x2 = ws + OFF_X2;
    float* x3 = ws + OFF_X3;
    unsigned short* x3h = (unsigned short*)(ws + OFF_X3H);
    float* codes = ws + OFF_CODES;
    int*   lab = (int*)(ws + OFF_LAB);
    float* cnt = ws + OFF_CNT;
    unsigned short* wph = (unsigned short*)(ws + OFF_WPH);
    unsigned short* wpl = (unsigned short*)(ws + OFF_WPL);
    float* out = (float*)d_out;

    // weight pack (independent of activations)
    packw_kernel<<<dim3(4608), TPB, 0, stream>>>(w3, wph, wpl);
    // stage 0: conv0 + IN + lrelu    -> x0 [4,32,256,256]
    conv0_kernel<<<dim3(256, 8, 4), TPB, 0, stream>>>(input, w0, b0, x0);
    in_lrelu_kernel<<<dim3(32, 4), TPB, 0, stream>>>(x0, 65536);
    // stage 1: s2 conv 32->64 + IN + lrelu -> x1
    conv_s2_kernel<32, 256, 256, 128, 128><<<dim3(64, 16, 4), TPB, 0, stream>>>(x0, w1, b1, x1, 64);
    in_lrelu_kernel<<<dim3(64, 4), TPB, 0, stream>>>(x1, 16384);
    // stage 2: s2 conv 64->128 + IN + lrelu -> x2
    conv_s2_kernel<64, 128, 128, 64, 64><<<dim3(16, 32, 4), TPB, 0, stream>>>(x1, w2, b2, x2, 128);
    in_lrelu_kernel<<<dim3(128, 4), TPB, 0, stream>>>(x2, 4096);
    // stage 3: convT 128->256 + IN + lrelu -> x3
    convt_kernel<<<dim3(16, 64, 8), TPB, 0, stream>>>(x2, wt, bt, x3);
    in_lrelu_kernel<<<dim3(256, 4), TPB, 0, stream>>>(x3, 16384);
    // stage 3.5: channel-last bf16 copy of x3
    transpose_bf16_kernel<<<dim3(8, 128, 4), TPB, 0, stream>>>(x3, x3h);
    // stage 4: conv3 (bf16 MFMA, split-A) + tanh -> codes
    conv3_mfma_kernel<<<dim3(8, 32, 4), 512, 0, stream>>>(x3h, wph, wpl, b3, codes);
    // stage 5: segment mean
    hipMemsetAsync(cnt, 0, 80 * sizeof(float), stream);
    label_kernel<<<dim3(64, 4), TPB, 0, stream>>>(segmap, fg, lab, cnt);
    segsum_kernel<<<dim3(512, 4), TPB, 0, stream>>>(codes, lab, cnt, out);
}

// Round 3
// 1036.858 us; speedup vs baseline: 3.5361x; 1.1756x over previous
//
#include <hip/hip_runtime.h>
#include <hip/hip_bf16.h>
#include <cstddef>

#define TPB 256

typedef float f32x4_t __attribute__((ext_vector_type(4)));
typedef __bf16 bf16x8_t __attribute__((ext_vector_type(8)));
typedef unsigned short u16x8_t __attribute__((ext_vector_type(8)));

// ---------------- workspace layout (float-element offsets) ----------------
// x0:   [4,32,256,256] f32     @ 0           (8,388,608)
// x1:   [4,64,128,128] f32     @ 8,388,608   (4,194,304)   (wtph/wtpl reuse after conv_s2(2))
// x2:   [4,128,64,64] f32      @ 12,582,912  (2,097,152)
// x2h:  [2][4,64,64,128] bf16  @ 14,680,064  (2,097,152)   hi/lo planes
// x3n:  [4,128,128,256] f32    @ 16,777,216  (16,777,216)  ends 33,554,432
// x3h:  [4,128,128,256] bf16   @ 0           (8,388,608)   x0 dead
// codes:[4,512,128,128] f32    @ 8,388,608   (33,554,432)  ends 41,943,040 (x1,x2,x2h,x3n,wt dead)
// stats:[4,256,2] f32          @ 41,943,040  (2048)        (reuses lab region, dead before label)
// lab:  [4,128,128] int        @ 41,943,040  (65,536)
// cnt:  [4,20] f32             @ 42,008,576  (80)
// wph:  [9,512,256] bf16       @ 42,008,704  (589,824)
// wpl:  [9,512,256] bf16       @ 42,598,528  (589,824)     ends 43,188,352
// wtph: [9,256,128] bf16       @ 8,388,608   (147,456)     in dead x1
// wtpl: [9,256,128] bf16       @ 8,536,064   (147,456)
static const size_t OFF_X0    = 0;
static const size_t OFF_X1    = 8388608;
static const size_t OFF_X2    = 12582912;
static const size_t OFF_X2H   = 14680064;
static const size_t OFF_X3N   = 16777216;
static const size_t OFF_X3H   = 0;
static const size_t OFF_CODES = 8388608;
static const size_t OFF_STATS = 41943040;
static const size_t OFF_LAB   = 41943040;
static const size_t OFF_CNT   = 42008576;
static const size_t OFF_WPH   = 42008704;
static const size_t OFF_WPL   = 42598528;
static const size_t OFF_WTPH  = 8388608;
static const size_t OFF_WTPL  = 8536064;

__device__ __forceinline__ unsigned short f2bf(float f) {
    unsigned int u = __float_as_uint(f);
    unsigned int r = u + 0x7FFFu + ((u >> 16) & 1u);   // RNE (finite inputs)
    return (unsigned short)(r >> 16);
}
__device__ __forceinline__ float bf2f(unsigned short h) {
    return __uint_as_float(((unsigned int)h) << 16);
}

// ---------------- conv0: 3->32, 256x256, reflect pad 1 ----------------
__global__ void conv0_kernel(const float* __restrict__ x, const float* __restrict__ w,
                             const float* __restrict__ bias, float* __restrict__ y) {
    int pix = blockIdx.x * TPB + threadIdx.x;
    int i = pix >> 8, j = pix & 255;
    int ocg = blockIdx.y, b = blockIdx.z;
    const float* xb = x + (size_t)b * 3 * 65536;
    float acc[4];
#pragma unroll
    for (int o = 0; o < 4; ++o) acc[o] = bias[ocg * 4 + o];
    for (int c = 0; c < 3; ++c) {
        const float* xc = xb + c * 65536;
        const float* wc = w + ((ocg * 4) * 3 + c) * 9;
#pragma unroll
        for (int u = 0; u < 3; ++u) {
            int ii = i + u - 1; ii = ii < 0 ? 1 : (ii > 255 ? 254 : ii);
#pragma unroll
            for (int v = 0; v < 3; ++v) {
                int jj = j + v - 1; jj = jj < 0 ? 1 : (jj > 255 ? 254 : jj);
                float xv = xc[(ii << 8) + jj];
#pragma unroll
                for (int o = 0; o < 4; ++o) acc[o] += xv * wc[o * 27 + u * 3 + v];
            }
        }
    }
    float* yb = y + ((size_t)(b * 32 + ocg * 4)) * 65536;
#pragma unroll
    for (int o = 0; o < 4; ++o) yb[o * 65536 + pix] = acc[o];
}

// ---------------- instance norm + leaky relu (in place, NCHW) ----------------
__global__ void in_lrelu_kernel(float* __restrict__ x, int HW) {
    size_t base = (size_t)(blockIdx.y * gridDim.x + blockIdx.x) * (size_t)HW;
    float* p = x + base;
    double s = 0.0, ss = 0.0;
    for (int k = threadIdx.x; k < HW; k += TPB) {
        float v = p[k];
        s += v; ss += (double)v * v;
    }
#pragma unroll
    for (int o = 32; o > 0; o >>= 1) {
        s  += __shfl_down(s, o);
        ss += __shfl_down(ss, o);
    }
    __shared__ double sh[2][4];
    int wv = threadIdx.x >> 6;
    if ((threadIdx.x & 63) == 0) { sh[0][wv] = s; sh[1][wv] = ss; }
    __syncthreads();
    if (threadIdx.x == 0) {
        double S  = sh[0][0] + sh[0][1] + sh[0][2] + sh[0][3];
        double SS = sh[1][0] + sh[1][1] + sh[1][2] + sh[1][3];
        double m = S / HW;
        double var = SS / HW - m * m;
        sh[0][0] = m;
        sh[1][0] = 1.0 / sqrt(var + 1e-5);
    }
    __syncthreads();
    float m = (float)sh[0][0], inv = (float)sh[1][0];
    for (int k = threadIdx.x; k < HW; k += TPB) {
        float v = (p[k] - m) * inv;
        p[k] = v >= 0.0f ? v : 0.2f * v;
    }
}

// ---------------- strided conv (stride 2, zero pad 1) ----------------
template<int IC, int IH, int IW, int OH, int OW>
__global__ void conv_s2_kernel(const float* __restrict__ x, const float* __restrict__ w,
                               const float* __restrict__ bias, float* __restrict__ y, int OC) {
    int pix = blockIdx.x * TPB + threadIdx.x;
    int i = pix / OW, j = pix % OW;
    int ocg = blockIdx.y, b = blockIdx.z;
    const float* xb = x + (size_t)b * IC * IH * IW;
    float acc[4];
#pragma unroll
    for (int o = 0; o < 4; ++o) acc[o] = bias[ocg * 4 + o];
    for (int c = 0; c < IC; ++c) {
        const float* xc = xb + c * IH * IW;
        const float* wc = w + ((ocg * 4) * IC + c) * 9;
#pragma unroll
        for (int u = 0; u < 3; ++u) {
            int ii = 2 * i + u - 1;
            if (ii < 0 || ii >= IH) continue;
#pragma unroll
            for (int v = 0; v < 3; ++v) {
                int jj = 2 * j + v - 1;
                if (jj < 0 || jj >= IW) continue;
                float xv = xc[ii * IW + jj];
#pragma unroll
                for (int o = 0; o < 4; ++o) acc[o] += xv * wc[o * IC * 9 + u * 3 + v];
            }
        }
    }
    float* yb = y + ((size_t)(b * OC) + ocg * 4) * (size_t)(OH * OW);
#pragma unroll
    for (int o = 0; o < 4; ++o) yb[o * OH * OW + pix] = acc[o];
}

// ---------------- transpose+split x2: [4,128,64,64] f32 -> [2][4,64,64,128] bf16 ----------------
// grid (64 h, 4 b), block 256
__global__ void transpose_x2_kernel(const float* __restrict__ x2, unsigned short* __restrict__ x2h) {
    __shared__ __align__(16) unsigned short tileH[64][136];
    __shared__ __align__(16) unsigned short tileL[64][136];
    int h = blockIdx.x, b = blockIdx.y;
    int t = threadIdx.x;
    int px = t & 63, c4 = t >> 6;
    const float* src = x2 + ((size_t)b * 128) * 4096 + h * 64 + px;
#pragma unroll
    for (int k = 0; k < 32; ++k) {
        int c = c4 * 32 + k;
        float v = src[(size_t)c * 4096];
        unsigned short hb = f2bf(v);
        tileH[px][c] = hb;
        tileL[px][c] = f2bf(v - bf2f(hb));
    }
    __syncthreads();
    unsigned short* dh = x2h + ((size_t)(b * 64 + h) * 64) * 128;
#pragma unroll
    for (int k = 0; k < 4; ++k) {
        int chunk = k * 256 + t;
        int p2 = chunk >> 4, c8 = (chunk & 15) << 3;
        *(u16x8_t*)&dh[(size_t)p2 * 128 + c8] = *(const u16x8_t*)&tileH[p2][c8];
        *(u16x8_t*)&dh[2097152 + (size_t)p2 * 128 + c8] = *(const u16x8_t*)&tileL[p2][c8];
    }
}

// ---------------- weight packs ----------------
// conv3: w3 [512,256,3,3] -> wph/wpl [9,512,256] bf16 hi/lo
__global__ void packw_kernel(const float* __restrict__ w3, unsigned short* __restrict__ wph,
                             unsigned short* __restrict__ wpl) {
    int id = blockIdx.x * TPB + threadIdx.x;
    if (id >= 9 * 512 * 256) return;
    int c = id & 255; int to = id >> 8; int o = to & 511; int tt = to >> 9;
    float v = w3[((size_t)o * 256 + c) * 9 + tt];
    unsigned short hb = f2bf(v);
    wph[id] = hb;
    wpl[id] = f2bf(v - bf2f(hb));
}
// convT: wt [256,128,3,3] -> wtph/wtpl [9,256,128] bf16 hi/lo
__global__ void packwt_kernel(const float* __restrict__ wt, unsigned short* __restrict__ wph,
                              unsigned short* __restrict__ wpl) {
    int id = blockIdx.x * TPB + threadIdx.x;
    if (id >= 9 * 256 * 128) return;
    int c = id & 127; int to = id >> 7; int o = to & 255; int tt = to >> 8;
    float v = wt[((size_t)o * 128 + c) * 9 + tt];
    unsigned short hb = f2bf(v);
    wph[id] = hb;
    wpl[id] = f2bf(v - bf2f(hb));
}

// ---------------- convT 128->256 as MFMA, parity class (PI,PJ) ----------------
// x2h: [2][4][64][64][128] bf16 (hi/lo). y: x3n [4][128][128][256] f32 (+bias, pre-IN).
// Block 512 thr / 8 waves: 64 oc x (8 a-rows x 64 bb-cols) of the 64x64 class grid.
// grid (4 ocg, 8 atile, 4 b). MFMA operand order: A=X (bb on D-rows), B=W (oc on D-cols)
// so NHWC writes are 64B-contiguous per quarter-wave. 3-term hi/lo split (~fp32 exact).
template<int PI, int PJ>
__global__ __launch_bounds__(512, 2) void convt_mfma_kernel(
    const unsigned short* __restrict__ xh, const unsigned short* __restrict__ wh,
    const unsigned short* __restrict__ wl, const float* __restrict__ bias,
    float* __restrict__ y) {
    constexpr int NT = (PI + 1) * (PJ + 1);
    __shared__ __align__(16) unsigned short ldsW[NT][2][64][32];
    __shared__ __align__(16) unsigned short ldsXh[9][66][32];
    __shared__ __align__(16) unsigned short ldsXl[9][66][32];
    int ocg = blockIdx.x, a0 = blockIdx.y * 8, b = blockIdx.z;
    int tid = threadIdx.x;
    int l = tid & 63, w = tid >> 6;
    int px = l & 15, g = l >> 4;

    f32x4_t acc[4][4];                       // [j (bb frag)][m (oc frag)]
#pragma unroll
    for (int m = 0; m < 4; ++m) {
        float bv = bias[ocg * 64 + 16 * m + px];
#pragma unroll
        for (int j = 0; j < 4; ++j)
#pragma unroll
            for (int r = 0; r < 4; ++r) acc[j][m][r] = bv;
    }
    unsigned short* ldsXhf = &ldsXh[0][0][0];
    unsigned short* ldsXlf = &ldsXl[0][0][0];

    for (int cc = 0; cc < 128; cc += 32) {
        __syncthreads();
        // ---- stage W: NT*2*64*32 elems, iter k stages tap k ----
#pragma unroll
        for (int k = 0; k < NT; ++k) {
            int iu = PJ ? (k >> 1) : k;
            int iv = PJ ? (k & 1) : 0;
            int u = PI ? iu * 2 : 1;
            int v = PJ ? iv * 2 : 1;
            int tap = 3 * u + v;
            int gq = tid & 3;
            int o = (tid >> 2) & 63;
            int h = (tid >> 8) & 1;
            const unsigned short* srcp = (h ? wl : wh) +
                ((size_t)tap * 256 + ocg * 64 + o) * 128 + cc + (gq << 3);
            *(u16x8_t*)&ldsW[k][h][o][(gq ^ (o & 3)) << 3] = *(const u16x8_t*)srcp;
        }
        // ---- stage X (hi+lo): 9*66*32 elems = 2376 chunks ----
#pragma unroll
        for (int k = 0; k < 5; ++k) {
            int c16 = k * 512 + tid;
            if (c16 < 2376) {
                int gq = c16 & 3;
                int rc = c16 >> 2;                  // 0..593
                int row = (rc * 993) >> 16;         // rc / 66
                int col = rc - row * 66;
                int gr = a0 + row;
                u16x8_t vh = {}, vl = {};
                if (gr < 64 && col < 64) {
                    size_t sidx = (((size_t)(b * 64 + gr) * 64) + col) * 128 + cc + (gq << 3);
                    vh = *(const u16x8_t*)(xh + sidx);
                    vl = *(const u16x8_t*)(xh + 2097152 + sidx);
                }
                int off = ((rc << 2) | (gq ^ (col & 3))) << 3;
                *(u16x8_t*)(ldsXhf + off) = vh;
                *(u16x8_t*)(ldsXlf + off) = vl;
            }
        }
        __syncthreads();
        // ---- compute ----
#pragma unroll
        for (int k = 0; k < NT; ++k) {
            int iu = PJ ? (k >> 1) : k;
            int iv = PJ ? (k & 1) : 0;
            int dr = iu, dc = iv;
            bf16x8_t Xh4[4], Xl4[4], Wh4[4], Wl4[4];
#pragma unroll
            for (int j = 0; j < 4; ++j) {
                int col = dc + 16 * j + px;
                int sl = (g ^ (col & 3)) << 3;
                Xh4[j] = *(const bf16x8_t*)&ldsXh[w + dr][col][sl];
                Xl4[j] = *(const bf16x8_t*)&ldsXl[w + dr][col][sl];
            }
            int sA = (g ^ (px & 3)) << 3;
#pragma unroll
            for (int m = 0; m < 4; ++m) {
                Wh4[m] = *(const bf16x8_t*)&ldsW[k][0][16 * m + px][sA];
                Wl4[m] = *(const bf16x8_t*)&ldsW[k][1][16 * m + px][sA];
            }
#pragma unroll
            for (int j = 0; j < 4; ++j)
#pragma unroll
                for (int m = 0; m < 4; ++m) {
                    acc[j][m] = __builtin_amdgcn_mfma_f32_16x16x32_bf16(Xh4[j], Wh4[m], acc[j][m], 0, 0, 0);
                    acc[j][m] = __builtin_amdgcn_mfma_f32_16x16x32_bf16(Xh4[j], Wl4[m], acc[j][m], 0, 0, 0);
                    acc[j][m] = __builtin_amdgcn_mfma_f32_16x16x32_bf16(Xl4[j], Wh4[m], acc[j][m], 0, 0, 0);
                }
        }
    }
    // ---- epilogue: D row(reg: 4g+r)=bb, col(lane&15)=oc ----
    int orow = 2 * (a0 + w) + PI;
    float* yb = y + (((size_t)(b * 128 + orow) * 128)) * 256 + ocg * 64;
#pragma unroll
    for (int j = 0; j < 4; ++j)
#pragma unroll
        for (int r = 0; r < 4; ++r) {
            int bb = 16 * j + 4 * g + r;
            float* yp = yb + (size_t)(2 * bb + PJ) * 256;
#pragma unroll
            for (int m = 0; m < 4; ++m)
                yp[16 * m + px] = acc[j][m][r];
        }
}

// ---------------- NHWC instance-norm stats / apply (x3n -> x3h bf16) ----------------
__global__ void in_stats_nhwc_kernel(const float* __restrict__ x, float* __restrict__ stats) {
    int row = blockIdx.x, b = blockIdx.y;
    int c = threadIdx.x;
    const float* p = x + ((size_t)(b * 128 + row) * 128) * 256 + c;
    float s = 0.f, ss = 0.f;
    for (int col = 0; col < 128; ++col) {
        float v = p[(size_t)col * 256];
        s += v; ss += v * v;
    }
    atomicAdd(&stats[(b * 256 + c) * 2], s);
    atomicAdd(&stats[(b * 256 + c) * 2 + 1], ss);
}
__global__ void in_apply_nhwc_kernel(const float* __restrict__ x, const float* __restrict__ stats,
                                     unsigned short* __restrict__ xhout) {
    int row = blockIdx.x, b = blockIdx.y;
    int c = threadIdx.x;
    float s = stats[(b * 256 + c) * 2], ss = stats[(b * 256 + c) * 2 + 1];
    float m = s * (1.f / 16384.f);
    float var = ss * (1.f / 16384.f) - m * m;
    float inv = rsqrtf(var + 1e-5f);
    const float* p = x + ((size_t)(b * 128 + row) * 128) * 256 + c;
    unsigned short* q = xhout + ((size_t)(b * 128 + row) * 128) * 256 + c;
    for (int col = 0; col < 128; ++col) {
        float v = (p[(size_t)col * 256] - m) * inv;
        v = v >= 0.f ? v : 0.2f * v;
        q[(size_t)col * 256] = f2bf(v);
    }
}

// ---------------- conv3: 256->512 @128x128, reflect pad, bias+tanh, bf16 MFMA ----------------
// As round 2, plus XOR bank-swizzle on the 16B ic-slot: slot = g ^ (col & 3).
__global__ __launch_bounds__(512, 2) void conv3_mfma_kernel(
    const unsigned short* __restrict__ xh, const unsigned short* __restrict__ wh,
    const unsigned short* __restrict__ wl, const float* __restrict__ bias,
    float* __restrict__ y) {
    __shared__ __align__(16) unsigned short ldsW[9][2][64][32];
    __shared__ __align__(16) unsigned short ldsX[10][66][32];
    int ocg = blockIdx.x;
    int tr = blockIdx.y >> 1, tc = blockIdx.y & 1;
    int b = blockIdx.z;
    int tid = threadIdx.x;
    int l = tid & 63, w = tid >> 6;
    int px = l & 15, g = l >> 4;
    int r0 = tr * 8, c0 = tc * 64;

    f32x4_t acc[4][4];
#pragma unroll
    for (int m = 0; m < 4; ++m)
#pragma unroll
        for (int r = 0; r < 4; ++r) {
            float bv = bias[ocg * 64 + 16 * m + 4 * g + r];
#pragma unroll
            for (int j = 0; j < 4; ++j) acc[m][j][r] = bv;
        }

    const unsigned short* xbase = xh + (size_t)b * (128 * 128 * 256);
    unsigned short* ldsWf = &ldsW[0][0][0][0];
    unsigned short* ldsXf = &ldsX[0][0][0];

    for (int cc = 0; cc < 256; cc += 32) {
        __syncthreads();
        // ---- stage W ----
#pragma unroll
        for (int k = 0; k < 9; ++k) {
            int c16 = (k << 9) + tid;
            int gq = c16 & 3;
            int hto = c16 >> 2;
            int o = hto & 63;
            int th = hto >> 6;
            int h = th & 1, ttap = th >> 1;
            const unsigned short* srcp = (h ? wl : wh) +
                (((size_t)ttap * 512 + ocg * 64 + o) << 8) + cc + (gq << 3);
            *(u16x8_t*)(ldsWf + (((hto << 2) | (gq ^ (o & 3))) << 3)) = *(const u16x8_t*)srcp;
        }
        // ---- stage X ----
#pragma unroll
        for (int k = 0; k < 6; ++k) {
            int c16 = (k << 9) + tid;
            if (c16 < 2640) {
                int gq = c16 & 3;
                int rc = c16 >> 2;
                int row = (rc * 993) >> 16;      // rc / 66
                int col = rc - row * 66;
                int gi = r0 + row - 1; gi = gi < 0 ? 1 : (gi > 127 ? 126 : gi);
                int gj = c0 + col - 1; gj = gj < 0 ? 1 : (gj > 127 ? 126 : gj);
                const unsigned short* srcp = xbase + (((size_t)(gi << 7) + gj) << 8) + cc + (gq << 3);
                *(u16x8_t*)(ldsXf + (((rc << 2) | (gq ^ (col & 3))) << 3)) = *(const u16x8_t*)srcp;
            }
        }
        __syncthreads();
        // ---- compute ----
#pragma unroll
        for (int u = 0; u < 3; ++u) {
#pragma unroll
            for (int v = 0; v < 3; ++v) {
                int t3 = 3 * u + v;
                bf16x8_t Ah[4], Al[4], Bf[4];
                int sA = (g ^ (px & 3)) << 3;
#pragma unroll
                for (int m = 0; m < 4; ++m) {
                    Ah[m] = *(const bf16x8_t*)&ldsW[t3][0][16 * m + px][sA];
                    Al[m] = *(const bf16x8_t*)&ldsW[t3][1][16 * m + px][sA];
                }
#pragma unroll
                for (int j = 0; j < 4; ++j) {
                    int colX = v + 16 * j + px;
                    Bf[j] = *(const bf16x8_t*)&ldsX[w + u][colX][(g ^ (colX & 3)) << 3];
                }
#pragma unroll
                for (int m = 0; m < 4; ++m)
#pragma unroll
                    for (int j = 0; j < 4; ++j) {
                        acc[m][j] = __builtin_amdgcn_mfma_f32_16x16x32_bf16(Ah[m], Bf[j], acc[m][j], 0, 0, 0);
                        acc[m][j] = __builtin_amdgcn_mfma_f32_16x16x32_bf16(Al[m], Bf[j], acc[m][j], 0, 0, 0);
                    }
            }
        }
    }
    float* yb = y + ((size_t)(b * 512 + ocg * 64)) * 16384;
    int row = r0 + w;
#pragma unroll
    for (int m = 0; m < 4; ++m)
#pragma unroll
        for (int r = 0; r < 4; ++r) {
            int oc = 16 * m + 4 * g + r;
            float* yp = yb + (size_t)oc * 16384 + (row << 7) + c0;
#pragma unroll
            for (int j = 0; j < 4; ++j)
                yp[16 * j + px] = tanhf(acc[m][j][r]);
        }
}

// ---------------- labels + counts ----------------
__global__ void label_kernel(const float* __restrict__ seg, const float* __restrict__ fg,
                             int* __restrict__ lab, float* __restrict__ counts) {
    int b = blockIdx.y;
    int pix = blockIdx.x * TPB + threadIdx.x;
    int i = pix >> 7, j = pix & 127;
    int src = ((i * 2) << 8) + (j * 2);
    const float* fgb = fg + (size_t)b * 65536;
    int l = -1;
    if (fgb[src] == 0.0f) {
        const float* sb = seg + (size_t)b * 20 * 65536;
        for (int s = 0; s < 20; ++s)
            if (sb[(size_t)s * 65536 + src] != 0.0f) { l = s; break; }
    }
    lab[b * 16384 + pix] = l;
    __shared__ int bins[20];
    if (threadIdx.x < 20) bins[threadIdx.x] = 0;
    __syncthreads();
    if (l >= 0) atomicAdd(&bins[l], 1);
    __syncthreads();
    if (threadIdx.x < 20 && bins[threadIdx.x] > 0)
        atomicAdd(&counts[b * 20 + threadIdx.x], (float)bins[threadIdx.x]);
}

// ---------------- segment sums + divide ----------------
__global__ void segsum_kernel(const float* __restrict__ codes, const int* __restrict__ lab,
                              const float* __restrict__ counts, float* __restrict__ out) {
    int f = blockIdx.x, b = blockIdx.y;
    const float* cb = codes + ((size_t)(b * 512 + f)) * 16384;
    const int* lb = lab + b * 16384;
    __shared__ float bins[4][20];
    for (int k = threadIdx.x; k < 80; k += TPB) bins[k / 20][k % 20] = 0.0f;
    __syncthreads();
    int wv = threadIdx.x >> 6;
    for (int p = threadIdx.x; p < 16384; p += TPB) {
        float v = cb[p];
        int l = lb[p];
        if (l >= 0) atomicAdd(&bins[wv][l], v);
    }
    __syncthreads();
    if (threadIdx.x < 20) {
        int s = threadIdx.x;
        float t = bins[0][s] + bins[1][s] + bins[2][s] + bins[3][s];
        float c = counts[b * 20 + s];
        out[((size_t)(b * 20 + s)) * 512 + f] = c > 0.0f ? t / c : 0.0f;
    }
}

// ---------------- launch ----------------
extern "C" void kernel_launch(void* const* d_in, const int* in_sizes, int n_in,
                              void* d_out, int out_size, void* d_ws, size_t ws_size,
                              hipStream_t stream) {
    const float* input = (const float*)d_in[0];
    const float* segmap = (const float*)d_in[1];
    const float* fg = (const float*)d_in[2];
    const float* w0 = (const float*)d_in[3];  const float* b0 = (const float*)d_in[4];
    const float* w1 = (const float*)d_in[5];  const float* b1 = (const float*)d_in[6];
    const float* w2 = (const float*)d_in[7];  const float* b2 = (const float*)d_in[8];
    const float* wt = (const float*)d_in[9];  const float* bt = (const float*)d_in[10];
    const float* w3 = (const float*)d_in[11]; const float* b3 = (const float*)d_in[12];

    float* ws = (float*)d_ws;
    float* x0 = ws + OFF_X0;
    float* x1 = ws + OFF_X1;
    float* x2 = ws + OFF_X2;
    unsigned short* x2h = (unsigned short*)(ws + OFF_X2H);
    float* x3n = ws + OFF_X3N;
    unsigned short* x3h = (unsigned short*)(ws + OFF_X3H);
    float* codes = ws + OFF_CODES;
    float* stats = ws + OFF_STATS;
    int*   lab = (int*)(ws + OFF_LAB);
    float* cnt = ws + OFF_CNT;
    unsigned short* wph = (unsigned short*)(ws + OFF_WPH);
    unsigned short* wpl = (unsigned short*)(ws + OFF_WPL);
    unsigned short* wtph = (unsigned short*)(ws + OFF_WTPH);
    unsigned short* wtpl = (unsigned short*)(ws + OFF_WTPL);
    float* out = (float*)d_out;

    // conv3 weight pack (independent)
    packw_kernel<<<dim3(4608), TPB, 0, stream>>>(w3, wph, wpl);
    // stage 0: conv0 + IN + lrelu -> x0
    conv0_kernel<<<dim3(256, 8, 4), TPB, 0, stream>>>(input, w0, b0, x0);
    in_lrelu_kernel<<<dim3(32, 4), TPB, 0, stream>>>(x0, 65536);
    // stage 1: s2 conv 32->64 + IN + lrelu -> x1
    conv_s2_kernel<32, 256, 256, 128, 128><<<dim3(64, 16, 4), TPB, 0, stream>>>(x0, w1, b1, x1, 64);
    in_lrelu_kernel<<<dim3(64, 4), TPB, 0, stream>>>(x1, 16384);
    // stage 2: s2 conv 64->128 + IN + lrelu -> x2
    conv_s2_kernel<64, 128, 128, 64, 64><<<dim3(16, 32, 4), TPB, 0, stream>>>(x1, w2, b2, x2, 128);
    // convT weight pack AFTER conv_s2(2) (reuses dead x1 region)
    packwt_kernel<<<dim3(1152), TPB, 0, stream>>>(wt, wtph, wtpl);
    in_lrelu_kernel<<<dim3(128, 4), TPB, 0, stream>>>(x2, 4096);
    // stage 3: transpose x2 -> NHWC bf16 hi/lo, then convT (4 parity classes) -> x3n (+bias)
    transpose_x2_kernel<<<dim3(64, 4), TPB, 0, stream>>>(x2, x2h);
    convt_mfma_kernel<0, 0><<<dim3(4, 8, 4), 512, 0, stream>>>(x2h, wtph, wtpl, bt, x3n);
    convt_mfma_kernel<0, 1><<<dim3(4, 8, 4), 512, 0, stream>>>(x2h, wtph, wtpl, bt, x3n);
    convt_mfma_kernel<1, 0><<<dim3(4, 8, 4), 512, 0, stream>>>(x2h, wtph, wtpl, bt, x3n);
    convt_mfma_kernel<1, 1><<<dim3(4, 8, 4), 512, 0, stream>>>(x2h, wtph, wtpl, bt, x3n);
    // stage 3.5: NHWC IN + lrelu + bf16 convert -> x3h
    hipMemsetAsync(stats, 0, 2048 * sizeof(float), stream);
    in_stats_nhwc_kernel<<<dim3(128, 4), TPB, 0, stream>>>(x3n, stats);
    in_apply_nhwc_kernel<<<dim3(128, 4), TPB, 0, stream>>>(x3n, stats, x3h);
    // stage 4: conv3 (bf16 MFMA, split-A) + tanh -> codes
    conv3_mfma_kernel<<<dim3(8, 32, 4), 512, 0, stream>>>(x3h, wph, wpl, b3, codes);
    // stage 5: segment mean
    hipMemsetAsync(cnt, 0, 80 * sizeof(float), stream);
    label_kernel<<<dim3(64, 4), TPB, 0, stream>>>(segmap, fg, lab, cnt);
    segsum_kernel<<<dim3(512, 4), TPB, 0, stream>>>(codes, lab, cnt, out);
}

// Round 4
// 1018.365 us; speedup vs baseline: 3.6003x; 1.0182x over previous
//
#include <hip/hip_runtime.h>
#include <hip/hip_bf16.h>
#include <cstddef>

#define TPB 256

typedef float f32x4_t __attribute__((ext_vector_type(4)));
typedef __bf16 bf16x8_t __attribute__((ext_vector_type(8)));
typedef unsigned short u16x8_t __attribute__((ext_vector_type(8)));

// ---------------- workspace layout (float-element offsets) ----------------
// x0:   [4,32,256,256] f32     @ 0           (8,388,608)
// x1:   [4,64,128,128] f32     @ 8,388,608   (4,194,304)   (wtph/wtpl reuse after conv_s2(2))
// x2:   [4,128,64,64] f32      @ 12,582,912  (2,097,152)
// x2h:  [2][4,64,64,128] bf16  @ 14,680,064  (2,097,152)   hi/lo planes
// x3n:  [4,128,128,256] f32    @ 16,777,216  (16,777,216)  ends 33,554,432
// x3h:  [4,128,128,256] bf16   @ 0           (8,388,608)   x0 dead
// codes:[4,512,128,128] f32    @ 8,388,608   (33,554,432)  ends 41,943,040
// stats:[4,256,2] f32          @ 41,943,040  (2048)        (dead before label)
// lab:  [4,128,128] int        @ 41,943,040  (65,536)
// cnt:  [4,20] f32             @ 42,008,576  (80)
// wph:  [9,512,256] bf16       @ 42,008,704  (589,824)
// wpl:  [9,512,256] bf16       @ 42,598,528  (589,824)     ends 43,188,352
// wtph: [9,256,128] bf16       @ 8,388,608   (147,456)     in dead x1
// wtpl: [9,256,128] bf16       @ 8,536,064   (147,456)
static const size_t OFF_X0    = 0;
static const size_t OFF_X1    = 8388608;
static const size_t OFF_X2    = 12582912;
static const size_t OFF_X2H   = 14680064;
static const size_t OFF_X3N   = 16777216;
static const size_t OFF_X3H   = 0;
static const size_t OFF_CODES = 8388608;
static const size_t OFF_STATS = 41943040;
static const size_t OFF_LAB   = 41943040;
static const size_t OFF_CNT   = 42008576;
static const size_t OFF_WPH   = 42008704;
static const size_t OFF_WPL   = 42598528;
static const size_t OFF_WTPH  = 8388608;
static const size_t OFF_WTPL  = 8536064;

__device__ __forceinline__ unsigned short f2bf(float f) {
    unsigned int u = __float_as_uint(f);
    unsigned int r = u + 0x7FFFu + ((u >> 16) & 1u);   // RNE (finite inputs)
    return (unsigned short)(r >> 16);
}
__device__ __forceinline__ float bf2f(unsigned short h) {
    return __uint_as_float(((unsigned int)h) << 16);
}

// ---------------- conv0: 3->32, 256x256, reflect pad 1 ----------------
// grid (256, 4), block 256. 1 px/thread, all 32 oc. Weights broadcast from LDS.
__global__ __launch_bounds__(256) void conv0b_kernel(const float* __restrict__ x,
                                                     const float* __restrict__ w,
                                                     const float* __restrict__ bias,
                                                     float* __restrict__ y) {
    __shared__ float lw[3 * 9 * 32];                 // [c][t][o]
    int pix = blockIdx.x * TPB + threadIdx.x;
    int i = pix >> 8, j = pix & 255;
    int b = blockIdx.y;
    for (int k = threadIdx.x; k < 864; k += TPB) {
        int o = k & 31; int ct = k >> 5; int t = ct % 9; int c = ct / 9;
        lw[k] = w[((size_t)o * 3 + c) * 9 + t];
    }
    __syncthreads();
    float acc[32];
#pragma unroll
    for (int o = 0; o < 32; ++o) acc[o] = bias[o];
    const float* xb = x + (size_t)b * 3 * 65536;
    for (int c = 0; c < 3; ++c) {
        const float* xc = xb + c * 65536;
        float xv[9];
#pragma unroll
        for (int u = 0; u < 3; ++u) {
            int ii = i + u - 1; ii = ii < 0 ? 1 : (ii > 255 ? 254 : ii);
#pragma unroll
            for (int v = 0; v < 3; ++v) {
                int jj = j + v - 1; jj = jj < 0 ? 1 : (jj > 255 ? 254 : jj);
                xv[u * 3 + v] = xc[(ii << 8) + jj];
            }
        }
        const float* lwc = &lw[c * 288];
#pragma unroll
        for (int t = 0; t < 9; ++t)
#pragma unroll
            for (int o4 = 0; o4 < 8; ++o4) {
                float4 w4 = *(const float4*)&lwc[t * 32 + o4 * 4];
                acc[o4 * 4 + 0] += xv[t] * w4.x;
                acc[o4 * 4 + 1] += xv[t] * w4.y;
                acc[o4 * 4 + 2] += xv[t] * w4.z;
                acc[o4 * 4 + 3] += xv[t] * w4.w;
            }
    }
    float* yb = y + (size_t)b * 32 * 65536;
#pragma unroll
    for (int o = 0; o < 32; ++o) yb[(size_t)o * 65536 + pix] = acc[o];
}

// ---------------- instance norm + leaky relu (in place, NCHW) ----------------
__global__ void in_lrelu_kernel(float* __restrict__ x, int HW) {
    size_t base = (size_t)(blockIdx.y * gridDim.x + blockIdx.x) * (size_t)HW;
    float* p = x + base;
    double s = 0.0, ss = 0.0;
    for (int k = threadIdx.x; k < HW; k += TPB) {
        float v = p[k];
        s += v; ss += (double)v * v;
    }
#pragma unroll
    for (int o = 32; o > 0; o >>= 1) {
        s  += __shfl_down(s, o);
        ss += __shfl_down(ss, o);
    }
    __shared__ double sh[2][4];
    int wv = threadIdx.x >> 6;
    if ((threadIdx.x & 63) == 0) { sh[0][wv] = s; sh[1][wv] = ss; }
    __syncthreads();
    if (threadIdx.x == 0) {
        double S  = sh[0][0] + sh[0][1] + sh[0][2] + sh[0][3];
        double SS = sh[1][0] + sh[1][1] + sh[1][2] + sh[1][3];
        double m = S / HW;
        double var = SS / HW - m * m;
        sh[0][0] = m;
        sh[1][0] = 1.0 / sqrt(var + 1e-5);
    }
    __syncthreads();
    float m = (float)sh[0][0], inv = (float)sh[1][0];
    for (int k = threadIdx.x; k < HW; k += TPB) {
        float v = (p[k] - m) * inv;
        p[k] = v >= 0.0f ? v : 0.2f * v;
    }
}

// ---------------- strided conv (stride 2, zero pad 1), broadcast weights ----------------
// 2 adjacent out-cols per thread, OCT oc per thread. grid (OH*OW/512, OC/OCT, B).
template<int IC, int IH, int IW, int OH, int OW, int OCT>
__global__ __launch_bounds__(256) void conv_s2b_kernel(const float* __restrict__ x,
                                                       const float* __restrict__ w,
                                                       const float* __restrict__ bias,
                                                       float* __restrict__ y, int OC) {
    __shared__ float lw[IC * 9 * OCT];               // [c][t][o]
    int p2 = (blockIdx.x * TPB + threadIdx.x) * 2;
    int i = p2 / OW, j = p2 % OW;                    // j even, j+1 < OW
    int ocg = blockIdx.y, b = blockIdx.z;
    for (int k = threadIdx.x; k < IC * 9 * OCT; k += TPB) {
        int o = k & (OCT - 1); int ct = k / OCT; int t = ct % 9; int c = ct / 9;
        lw[k] = w[((size_t)(ocg * OCT + o) * IC + c) * 9 + t];
    }
    __syncthreads();
    float acc0[OCT], acc1[OCT];
#pragma unroll
    for (int o = 0; o < OCT; ++o) { float bv = bias[ocg * OCT + o]; acc0[o] = bv; acc1[o] = bv; }
    const float* xb = x + (size_t)b * IC * IH * IW;
    for (int c = 0; c < IC; ++c) {
        const float* xc = xb + (size_t)c * IH * IW;
        float xr[3][5];
#pragma unroll
        for (int u = 0; u < 3; ++u) {
            int ii = 2 * i + u - 1;
            bool vr = (ii >= 0);                      // ii <= IH-1 always
#pragma unroll
            for (int vv = 0; vv < 5; ++vv) {
                int jj = 2 * j + vv - 1;              // jj <= IW-1 always
                xr[u][vv] = (vr && jj >= 0) ? xc[ii * IW + jj] : 0.0f;
            }
        }
        const float* lwc = &lw[c * 9 * OCT];
#pragma unroll
        for (int u = 0; u < 3; ++u)
#pragma unroll
            for (int v = 0; v < 3; ++v) {
                float a = xr[u][v], bx = xr[u][v + 2];
#pragma unroll
                for (int o4 = 0; o4 < OCT / 4; ++o4) {
                    float4 w4 = *(const float4*)&lwc[(u * 3 + v) * OCT + o4 * 4];
                    acc0[o4 * 4 + 0] += a * w4.x;  acc1[o4 * 4 + 0] += bx * w4.x;
                    acc0[o4 * 4 + 1] += a * w4.y;  acc1[o4 * 4 + 1] += bx * w4.y;
                    acc0[o4 * 4 + 2] += a * w4.z;  acc1[o4 * 4 + 2] += bx * w4.z;
                    acc0[o4 * 4 + 3] += a * w4.w;  acc1[o4 * 4 + 3] += bx * w4.w;
                }
            }
    }
    float* yb = y + ((size_t)(b * OC) + ocg * OCT) * (size_t)(OH * OW) + p2;
#pragma unroll
    for (int o = 0; o < OCT; ++o) {
        float2 v2 = make_float2(acc0[o], acc1[o]);
        *(float2*)&yb[(size_t)o * OH * OW] = v2;
    }
}

// ---------------- transpose+split x2: [4,128,64,64] f32 -> [2][4,64,64,128] bf16 ----------------
__global__ void transpose_x2_kernel(const float* __restrict__ x2, unsigned short* __restrict__ x2h) {
    __shared__ __align__(16) unsigned short tileH[64][136];
    __shared__ __align__(16) unsigned short tileL[64][136];
    int h = blockIdx.x, b = blockIdx.y;
    int t = threadIdx.x;
    int px = t & 63, c4 = t >> 6;
    const float* src = x2 + ((size_t)b * 128) * 4096 + h * 64 + px;
#pragma unroll
    for (int k = 0; k < 32; ++k) {
        int c = c4 * 32 + k;
        float v = src[(size_t)c * 4096];
        unsigned short hb = f2bf(v);
        tileH[px][c] = hb;
        tileL[px][c] = f2bf(v - bf2f(hb));
    }
    __syncthreads();
    unsigned short* dh = x2h + ((size_t)(b * 64 + h) * 64) * 128;
#pragma unroll
    for (int k = 0; k < 4; ++k) {
        int chunk = k * 256 + t;
        int p2 = chunk >> 4, c8 = (chunk & 15) << 3;
        *(u16x8_t*)&dh[(size_t)p2 * 128 + c8] = *(const u16x8_t*)&tileH[p2][c8];
        *(u16x8_t*)&dh[2097152 + (size_t)p2 * 128 + c8] = *(const u16x8_t*)&tileL[p2][c8];
    }
}

// ---------------- weight packs ----------------
__global__ void packw_kernel(const float* __restrict__ w3, unsigned short* __restrict__ wph,
                             unsigned short* __restrict__ wpl) {
    int id = blockIdx.x * TPB + threadIdx.x;
    if (id >= 9 * 512 * 256) return;
    int c = id & 255; int to = id >> 8; int o = to & 511; int tt = to >> 9;
    float v = w3[((size_t)o * 256 + c) * 9 + tt];
    unsigned short hb = f2bf(v);
    wph[id] = hb;
    wpl[id] = f2bf(v - bf2f(hb));
}
__global__ void packwt_kernel(const float* __restrict__ wt, unsigned short* __restrict__ wph,
                              unsigned short* __restrict__ wpl) {
    int id = blockIdx.x * TPB + threadIdx.x;
    if (id >= 9 * 256 * 128) return;
    int c = id & 127; int to = id >> 7; int o = to & 255; int tt = to >> 8;
    float v = wt[((size_t)o * 128 + c) * 9 + tt];
    unsigned short hb = f2bf(v);
    wph[id] = hb;
    wpl[id] = f2bf(v - bf2f(hb));
}

// ---------------- convT 128->256 MFMA, all 4 parity classes in one launch ----------------
// grid (4 ocg, 8 atile, 16 = b*4 + cls), block 512. Fused per-channel stats (sum, sumsq).
__global__ __launch_bounds__(512, 2) void convt_mfma_all_kernel(
    const unsigned short* __restrict__ xh, const unsigned short* __restrict__ wh,
    const unsigned short* __restrict__ wl, const float* __restrict__ bias,
    float* __restrict__ y, float* __restrict__ stats) {
    __shared__ __align__(16) unsigned short ldsW[4][2][64][32];
    __shared__ __align__(16) unsigned short ldsXh[9][66][32];
    __shared__ __align__(16) unsigned short ldsXl[9][66][32];
    __shared__ float sums[64][2];
    int ocg = blockIdx.x, a0 = blockIdx.y * 8;
    int b = blockIdx.z >> 2, cls = blockIdx.z & 3;
    int pi = cls >> 1, pj = cls & 1;
    int nt = (pi + 1) * (pj + 1);
    int tid = threadIdx.x;
    int l = tid & 63, w = tid >> 6;
    int px = l & 15, g = l >> 4;

    f32x4_t acc[4][4];                       // [j (bb frag)][m (oc frag)]
#pragma unroll
    for (int m = 0; m < 4; ++m) {
        float bv = bias[ocg * 64 + 16 * m + px];
#pragma unroll
        for (int j = 0; j < 4; ++j)
#pragma unroll
            for (int r = 0; r < 4; ++r) acc[j][m][r] = bv;
    }
    unsigned short* ldsXhf = &ldsXh[0][0][0];
    unsigned short* ldsXlf = &ldsXl[0][0][0];

    for (int cc = 0; cc < 128; cc += 32) {
        __syncthreads();
        // ---- stage W: per k, 512 chunks ----
        for (int k = 0; k < nt; ++k) {
            int iu = pj ? (k >> 1) : k;
            int iv = pj ? (k & 1) : 0;
            int u = pi ? iu * 2 : 1;
            int v = pj ? iv * 2 : 1;
            int tap = 3 * u + v;
            int gq = tid & 3;
            int o = (tid >> 2) & 63;
            int h = (tid >> 8) & 1;
            const unsigned short* srcp = (h ? wl : wh) +
                ((size_t)tap * 256 + ocg * 64 + o) * 128 + cc + (gq << 3);
            *(u16x8_t*)&ldsW[k][h][o][(gq ^ (o & 3)) << 3] = *(const u16x8_t*)srcp;
        }
        // ---- stage X (hi+lo): 2376 chunks ----
        for (int k = 0; k < 5; ++k) {
            int c16 = k * 512 + tid;
            if (c16 < 2376) {
                int gq = c16 & 3;
                int rc = c16 >> 2;                  // 0..593
                int row = (rc * 993) >> 16;         // rc / 66
                int col = rc - row * 66;
                int gr = a0 + row;
                u16x8_t vh = {}, vl = {};
                if (gr < 64 && col < 64) {
                    size_t sidx = (((size_t)(b * 64 + gr) * 64) + col) * 128 + cc + (gq << 3);
                    vh = *(const u16x8_t*)(xh + sidx);
                    vl = *(const u16x8_t*)(xh + 2097152 + sidx);
                }
                int off = ((rc << 2) | (gq ^ (col & 3))) << 3;
                *(u16x8_t*)(ldsXhf + off) = vh;
                *(u16x8_t*)(ldsXlf + off) = vl;
            }
        }
        __syncthreads();
        // ---- compute ----
        for (int k = 0; k < nt; ++k) {
            int dr = pj ? (k >> 1) : k;
            int dc = pj ? (k & 1) : 0;
            bf16x8_t Xh4[4], Xl4[4], Wh4[4], Wl4[4];
#pragma unroll
            for (int j = 0; j < 4; ++j) {
                int col = dc + 16 * j + px;
                int sl = (g ^ (col & 3)) << 3;
                Xh4[j] = *(const bf16x8_t*)&ldsXh[w + dr][col][sl];
                Xl4[j] = *(const bf16x8_t*)&ldsXl[w + dr][col][sl];
            }
            int sA = (g ^ (px & 3)) << 3;
#pragma unroll
            for (int m = 0; m < 4; ++m) {
                Wh4[m] = *(const bf16x8_t*)&ldsW[k][0][16 * m + px][sA];
                Wl4[m] = *(const bf16x8_t*)&ldsW[k][1][16 * m + px][sA];
            }
#pragma unroll
            for (int j = 0; j < 4; ++j)
#pragma unroll
                for (int m = 0; m < 4; ++m) {
                    acc[j][m] = __builtin_amdgcn_mfma_f32_16x16x32_bf16(Xh4[j], Wh4[m], acc[j][m], 0, 0, 0);
                    acc[j][m] = __builtin_amdgcn_mfma_f32_16x16x32_bf16(Xh4[j], Wl4[m], acc[j][m], 0, 0, 0);
                    acc[j][m] = __builtin_amdgcn_mfma_f32_16x16x32_bf16(Xl4[j], Wh4[m], acc[j][m], 0, 0, 0);
                }
        }
    }
    // ---- epilogue: write + fused per-channel stats ----
    if (tid < 128) (&sums[0][0])[tid] = 0.0f;
    __syncthreads();
    int orow = 2 * (a0 + w) + pi;
    float* yb = y + (((size_t)(b * 128 + orow) * 128)) * 256 + ocg * 64;
#pragma unroll
    for (int m = 0; m < 4; ++m) {
        float sm = 0.0f, ssm = 0.0f;
#pragma unroll
        for (int j = 0; j < 4; ++j)
#pragma unroll
            for (int r = 0; r < 4; ++r) {
                float val = acc[j][m][r];
                sm += val; ssm += val * val;
                int bb = 16 * j + 4 * g + r;
                yb[(size_t)(2 * bb + pj) * 256 + 16 * m + px] = val;
            }
        sm  += __shfl_xor(sm, 16);  sm  += __shfl_xor(sm, 32);
        ssm += __shfl_xor(ssm, 16); ssm += __shfl_xor(ssm, 32);
        if (g == 0) {
            atomicAdd(&sums[16 * m + px][0], sm);
            atomicAdd(&sums[16 * m + px][1], ssm);
        }
    }
    __syncthreads();
    if (tid < 64) {
        atomicAdd(&stats[((size_t)(b * 256) + ocg * 64 + tid) * 2 + 0], sums[tid][0]);
        atomicAdd(&stats[((size_t)(b * 256) + ocg * 64 + tid) * 2 + 1], sums[tid][1]);
    }
}

// ---------------- NHWC instance-norm apply (x3n -> x3h bf16) ----------------
__global__ void in_apply_nhwc_kernel(const float* __restrict__ x, const float* __restrict__ stats,
                                     unsigned short* __restrict__ xhout) {
    int row = blockIdx.x, b = blockIdx.y;
    int c = threadIdx.x;
    float s = stats[(b * 256 + c) * 2], ss = stats[(b * 256 + c) * 2 + 1];
    float m = s * (1.0f / 16384.0f);
    float var = ss * (1.0f / 16384.0f) - m * m;
    float inv = rsqrtf(var + 1e-5f);
    const float* p = x + ((size_t)(b * 128 + row) * 128) * 256 + c;
    unsigned short* q = xhout + ((size_t)(b * 128 + row) * 128) * 256 + c;
    for (int col = 0; col < 128; ++col) {
        float v = (p[(size_t)col * 256] - m) * inv;
        v = v >= 0.0f ? v : 0.2f * v;
        q[(size_t)col * 256] = f2bf(v);
    }
}

// ---------------- conv3: 256->512 @128x128, reflect pad, bias+tanh, bf16 MFMA ----------------
// Wave: 64 oc x 2 rows x 64 cols (acc 4x8 = 128 VGPR). Block: 8 waves = 16 rows.
// Reads/tap = 16 (8 A + 8 B) feeding 64 MFMAs (ratio 4.0 vs 2.67 before).
// LDS: W[9][2][64][32] 73,728B + X[18][66][32] 76,032B = 149,760B (1 block/CU, 2 waves/SIMD).
__global__ __launch_bounds__(512, 2) void conv3_mfma_kernel(
    const unsigned short* __restrict__ xh, const unsigned short* __restrict__ wh,
    const unsigned short* __restrict__ wl, const float* __restrict__ bias,
    float* __restrict__ y) {
    __shared__ __align__(16) unsigned short ldsW[9][2][64][32];
    __shared__ __align__(16) unsigned short ldsX[18][66][32];
    int ocg = blockIdx.x;
    int tr = blockIdx.y >> 1, tc = blockIdx.y & 1;
    int b = blockIdx.z;
    int tid = threadIdx.x;
    int l = tid & 63, w = tid >> 6;
    int px = l & 15, g = l >> 4;
    int r0 = tr * 16, c0 = tc * 64;

    f32x4_t acc[4][8];
#pragma unroll
    for (int m = 0; m < 4; ++m)
#pragma unroll
        for (int r = 0; r < 4; ++r) {
            float bv = bias[ocg * 64 + 16 * m + 4 * g + r];
#pragma unroll
            for (int n = 0; n < 8; ++n) acc[m][n][r] = bv;
        }

    const unsigned short* xbase = xh + (size_t)b * (128 * 128 * 256);
    unsigned short* ldsWf = &ldsW[0][0][0][0];
    unsigned short* ldsXf = &ldsX[0][0][0];

    for (int cc = 0; cc < 256; cc += 32) {
        __syncthreads();
        // ---- stage W: 4608 chunks, 9 iters ----
#pragma unroll
        for (int k = 0; k < 9; ++k) {
            int c16 = (k << 9) + tid;
            int gq = c16 & 3;
            int hto = c16 >> 2;
            int o = hto & 63;
            int th = hto >> 6;
            int h = th & 1, ttap = th >> 1;
            const unsigned short* srcp = (h ? wl : wh) +
                (((size_t)ttap * 512 + ocg * 64 + o) << 8) + cc + (gq << 3);
            *(u16x8_t*)(ldsWf + (((hto << 2) | (gq ^ (o & 3))) << 3)) = *(const u16x8_t*)srcp;
        }
        // ---- stage X: 18*66*4 = 4752 chunks, 10 iters guarded ----
#pragma unroll
        for (int k = 0; k < 10; ++k) {
            int c16 = (k << 9) + tid;
            if (c16 < 4752) {
                int gq = c16 & 3;
                int rc = c16 >> 2;                 // 0..1187
                int row = (rc * 993) >> 16;        // rc / 66 (exact for rc < 32802)
                int col = rc - row * 66;
                int gi = r0 + row - 1; gi = gi < 0 ? 1 : (gi > 127 ? 126 : gi);
                int gj = c0 + col - 1; gj = gj < 0 ? 1 : (gj > 127 ? 126 : gj);
                const unsigned short* srcp = xbase + (((size_t)(gi << 7) + gj) << 8) + cc + (gq << 3);
                *(u16x8_t*)(ldsXf + (((rc << 2) | (gq ^ (col & 3))) << 3)) = *(const u16x8_t*)srcp;
            }
        }
        __syncthreads();
        // ---- compute: 9 taps x (8 A reads + 8 B reads -> 64 MFMAs) ----
#pragma unroll
        for (int u = 0; u < 3; ++u) {
#pragma unroll
            for (int v = 0; v < 3; ++v) {
                int t3 = 3 * u + v;
                bf16x8_t Ah[4], Al[4], Bf[2][4];
                int sA = (g ^ (px & 3)) << 3;
#pragma unroll
                for (int m = 0; m < 4; ++m) {
                    Ah[m] = *(const bf16x8_t*)&ldsW[t3][0][16 * m + px][sA];
                    Al[m] = *(const bf16x8_t*)&ldsW[t3][1][16 * m + px][sA];
                }
#pragma unroll
                for (int d = 0; d < 2; ++d)
#pragma unroll
                    for (int jj = 0; jj < 4; ++jj) {
                        int colX = v + 16 * jj + px;
                        Bf[d][jj] = *(const bf16x8_t*)&ldsX[2 * w + d + u][colX][(g ^ (colX & 3)) << 3];
                    }
                // all-hi then all-lo: no dependent back-to-back MFMA pairs
#pragma unroll
                for (int m = 0; m < 4; ++m)
#pragma unroll
                    for (int d = 0; d < 2; ++d)
#pragma unroll
                        for (int jj = 0; jj < 4; ++jj)
                            acc[m][d * 4 + jj] = __builtin_amdgcn_mfma_f32_16x16x32_bf16(
                                Ah[m], Bf[d][jj], acc[m][d * 4 + jj], 0, 0, 0);
#pragma unroll
                for (int m = 0; m < 4; ++m)
#pragma unroll
                    for (int d = 0; d < 2; ++d)
#pragma unroll
                        for (int jj = 0; jj < 4; ++jj)
                            acc[m][d * 4 + jj] = __builtin_amdgcn_mfma_f32_16x16x32_bf16(
                                Al[m], Bf[d][jj], acc[m][d * 4 + jj], 0, 0, 0);
            }
        }
    }
    float* yb = y + ((size_t)(b * 512 + ocg * 64)) * 16384;
#pragma unroll
    for (int m = 0; m < 4; ++m)
#pragma unroll
        for (int r = 0; r < 4; ++r) {
            int oc = 16 * m + 4 * g + r;
#pragma unroll
            for (int d = 0; d < 2; ++d) {
                int row = r0 + 2 * w + d;
                float* yp = yb + (size_t)oc * 16384 + (row << 7) + c0;
#pragma unroll
                for (int jj = 0; jj < 4; ++jj)
                    yp[16 * jj + px] = tanhf(acc[m][d * 4 + jj][r]);
            }
        }
}

// ---------------- labels + counts ----------------
__global__ void label_kernel(const float* __restrict__ seg, const float* __restrict__ fg,
                             int* __restrict__ lab, float* __restrict__ counts) {
    int b = blockIdx.y;
    int pix = blockIdx.x * TPB + threadIdx.x;
    int i = pix >> 7, j = pix & 127;
    int src = ((i * 2) << 8) + (j * 2);
    const float* fgb = fg + (size_t)b * 65536;
    int l = -1;
    if (fgb[src] == 0.0f) {
        const float* sb = seg + (size_t)b * 20 * 65536;
        for (int s = 0; s < 20; ++s)
            if (sb[(size_t)s * 65536 + src] != 0.0f) { l = s; break; }
    }
    lab[b * 16384 + pix] = l;
    __shared__ int bins[20];
    if (threadIdx.x < 20) bins[threadIdx.x] = 0;
    __syncthreads();
    if (l >= 0) atomicAdd(&bins[l], 1);
    __syncthreads();
    if (threadIdx.x < 20 && bins[threadIdx.x] > 0)
        atomicAdd(&counts[b * 20 + threadIdx.x], (float)bins[threadIdx.x]);
}

// ---------------- segment sums + divide ----------------
__global__ void segsum_kernel(const float* __restrict__ codes, const int* __restrict__ lab,
                              const float* __restrict__ counts, float* __restrict__ out) {
    int f = blockIdx.x, b = blockIdx.y;
    const float* cb = codes + ((size_t)(b * 512 + f)) * 16384;
    const int* lb = lab + b * 16384;
    __shared__ float bins[4][20];
    for (int k = threadIdx.x; k < 80; k += TPB) bins[k / 20][k % 20] = 0.0f;
    __syncthreads();
    int wv = threadIdx.x >> 6;
    for (int p = threadIdx.x; p < 16384; p += TPB) {
        float v = cb[p];
        int l = lb[p];
        if (l >= 0) atomicAdd(&bins[wv][l], v);
    }
    __syncthreads();
    if (threadIdx.x < 20) {
        int s = threadIdx.x;
        float t = bins[0][s] + bins[1][s] + bins[2][s] + bins[3][s];
        float c = counts[b * 20 + s];
        out[((size_t)(b * 20 + s)) * 512 + f] = c > 0.0f ? t / c : 0.0f;
    }
}

// ---------------- launch ----------------
extern "C" void kernel_launch(void* const* d_in, const int* in_sizes, int n_in,
                              void* d_out, int out_size, void* d_ws, size_t ws_size,
                              hipStream_t stream) {
    const float* input = (const float*)d_in[0];
    const float* segmap = (const float*)d_in[1];
    const float* fg = (const float*)d_in[2];
    const float* w0 = (const float*)d_in[3];  const float* b0 = (const float*)d_in[4];
    const float* w1 = (const float*)d_in[5];  const float* b1 = (const float*)d_in[6];
    const float* w2 = (const float*)d_in[7];  const float* b2 = (const float*)d_in[8];
    const float* wt = (const float*)d_in[9];  const float* bt = (const float*)d_in[10];
    const float* w3 = (const float*)d_in[11]; const float* b3 = (const float*)d_in[12];

    float* ws = (float*)d_ws;
    float* x0 = ws + OFF_X0;
    float* x1 = ws + OFF_X1;
    float* x2 = ws + OFF_X2;
    unsigned short* x2h = (unsigned short*)(ws + OFF_X2H);
    float* x3n = ws + OFF_X3N;
    unsigned short* x3h = (unsigned short*)(ws + OFF_X3H);
    float* codes = ws + OFF_CODES;
    float* stats = ws + OFF_STATS;
    int*   lab = (int*)(ws + OFF_LAB);
    float* cnt = ws + OFF_CNT;
    unsigned short* wph = (unsigned short*)(ws + OFF_WPH);
    unsigned short* wpl = (unsigned short*)(ws + OFF_WPL);
    unsigned short* wtph = (unsigned short*)(ws + OFF_WTPH);
    unsigned short* wtpl = (unsigned short*)(ws + OFF_WTPL);
    float* out = (float*)d_out;

    // conv3 weight pack (independent)
    packw_kernel<<<dim3(4608), TPB, 0, stream>>>(w3, wph, wpl);
    // stage 0: conv0 + IN + lrelu -> x0
    conv0b_kernel<<<dim3(256, 4), TPB, 0, stream>>>(input, w0, b0, x0);
    in_lrelu_kernel<<<dim3(32, 4), TPB, 0, stream>>>(x0, 65536);
    // stage 1: s2 conv 32->64 + IN + lrelu -> x1
    conv_s2b_kernel<32, 256, 256, 128, 128, 16><<<dim3(32, 4, 4), TPB, 0, stream>>>(x0, w1, b1, x1, 64);
    in_lrelu_kernel<<<dim3(64, 4), TPB, 0, stream>>>(x1, 16384);
    // stage 2: s2 conv 64->128 + IN + lrelu -> x2
    conv_s2b_kernel<64, 128, 128, 64, 64, 16><<<dim3(8, 8, 4), TPB, 0, stream>>>(x1, w2, b2, x2, 128);
    // convT weight pack AFTER conv_s2(2) (reuses dead x1 region)
    packwt_kernel<<<dim3(1152), TPB, 0, stream>>>(wt, wtph, wtpl);
    in_lrelu_kernel<<<dim3(128, 4), TPB, 0, stream>>>(x2, 4096);
    // stage 3: transpose x2 -> NHWC bf16 hi/lo; convT (all classes, fused stats) -> x3n
    transpose_x2_kernel<<<dim3(64, 4), TPB, 0, stream>>>(x2, x2h);
    hipMemsetAsync(stats, 0, 2048 * sizeof(float), stream);
    convt_mfma_all_kernel<<<dim3(4, 8, 16), 512, 0, stream>>>(x2h, wtph, wtpl, bt, x3n, stats);
    // stage 3.5: NHWC IN + lrelu + bf16 convert -> x3h
    in_apply_nhwc_kernel<<<dim3(128, 4), TPB, 0, stream>>>(x3n, stats, x3h);
    // stage 4: conv3 (bf16 MFMA, split-A) + tanh -> codes
    conv3_mfma_kernel<<<dim3(8, 16, 4), 512, 0, stream>>>(x3h, wph, wpl, b3, codes);
    // stage 5: segment mean
    hipMemsetAsync(cnt, 0, 80 * sizeof(float), stream);
    label_kernel<<<dim3(64, 4), TPB, 0, stream>>>(segmap, fg, lab, cnt);
    segsum_kernel<<<dim3(512, 4), TPB, 0, stream>>>(codes, lab, cnt, out);
}

// Round 5
// 815.149 us; speedup vs baseline: 4.4979x; 1.2493x over previous
//
#include <hip/hip_runtime.h>
#include <hip/hip_bf16.h>
#include <cstddef>

#define TPB 256

typedef float f32x4_t __attribute__((ext_vector_type(4)));
typedef __bf16 bf16x8_t __attribute__((ext_vector_type(8)));
typedef unsigned short u16x8_t __attribute__((ext_vector_type(8)));

// ---------------- workspace layout (float-element offsets) ----------------
// x0:   [4,32,256,256] f32     @ 0           (8,388,608)
// x1:   [4,64,128,128] f32     @ 8,388,608   (4,194,304)   (wtph/wtpl reuse after conv_s2(2))
// x2:   [4,128,64,64] f32      @ 12,582,912  (2,097,152)
// x2h:  [2][4,64,64,128] bf16  @ 14,680,064  (2,097,152)   hi/lo planes
// x3n:  [4,128,128,256] f32    @ 16,777,216  (16,777,216)  ends 33,554,432
// x3h:  [4,128,128,256] bf16   @ 0           (8,388,608)   x0 dead by then
// lab:  [4,128,128] int        @ 33,554,432  (65,536)
// cnt:  [4,20] f32             @ 33,619,968  (80)          \
// stats:[4,256,2] f32          @ 33,620,048  (2048)         | one memset
// gbins:[4,20,512] f32         @ 33,622,096  (40,960)       |
// nst:  [4,(32+64+128),2] f32  @ 33,663,056  (1792)        /  ends 33,664,848
// wph:  [9,512,256] bf16       @ 42,008,704  (589,824)
// wpl:  [9,512,256] bf16       @ 42,598,528  (589,824)     ends 43,188,352
// wtph: [9,256,128] bf16       @ 8,388,608   (147,456)     in dead x1
// wtpl: [9,256,128] bf16       @ 8,536,064   (147,456)
static const size_t OFF_X0    = 0;
static const size_t OFF_X1    = 8388608;
static const size_t OFF_X2    = 12582912;
static const size_t OFF_X2H   = 14680064;
static const size_t OFF_X3N   = 16777216;
static const size_t OFF_X3H   = 0;
static const size_t OFF_LAB   = 33554432;
static const size_t OFF_CNT   = 33619968;
static const size_t OFF_STATS = 33620048;
static const size_t OFF_GBINS = 33622096;
static const size_t OFF_NST0  = 33663056;                  // x0 stats: 256
static const size_t OFF_NST1  = 33663312;                  // x1 stats: 512
static const size_t OFF_NST2  = 33663824;                  // x2 stats: 1024 (ends 33,664,848)
static const size_t OFF_WPH   = 42008704;
static const size_t OFF_WPL   = 42598528;
static const size_t OFF_WTPH  = 8388608;
static const size_t OFF_WTPL  = 8536064;

__device__ __forceinline__ unsigned short f2bf(float f) {
    unsigned int u = __float_as_uint(f);
    unsigned int r = u + 0x7FFFu + ((u >> 16) & 1u);   // RNE (finite inputs)
    return (unsigned short)(r >> 16);
}
__device__ __forceinline__ float bf2f(unsigned short h) {
    return __uint_as_float(((unsigned int)h) << 16);
}
__device__ __forceinline__ void gload16(const unsigned short* g, unsigned short* l) {
    __builtin_amdgcn_global_load_lds((const __attribute__((address_space(1))) unsigned int*)g,
                                     (__attribute__((address_space(3))) unsigned int*)l, 16, 0, 0);
}

// ---------------- conv0: 3->32, 256x256, reflect pad 1 ----------------
__global__ __launch_bounds__(256) void conv0b_kernel(const float* __restrict__ x,
                                                     const float* __restrict__ w,
                                                     const float* __restrict__ bias,
                                                     float* __restrict__ y) {
    __shared__ float lw[3 * 9 * 32];                 // [c][t][o]
    int pix = blockIdx.x * TPB + threadIdx.x;
    int i = pix >> 8, j = pix & 255;
    int b = blockIdx.y;
    for (int k = threadIdx.x; k < 864; k += TPB) {
        int o = k & 31; int ct = k >> 5; int t = ct % 9; int c = ct / 9;
        lw[k] = w[((size_t)o * 3 + c) * 9 + t];
    }
    __syncthreads();
    float acc[32];
#pragma unroll
    for (int o = 0; o < 32; ++o) acc[o] = bias[o];
    const float* xb = x + (size_t)b * 3 * 65536;
    for (int c = 0; c < 3; ++c) {
        const float* xc = xb + c * 65536;
        float xv[9];
#pragma unroll
        for (int u = 0; u < 3; ++u) {
            int ii = i + u - 1; ii = ii < 0 ? 1 : (ii > 255 ? 254 : ii);
#pragma unroll
            for (int v = 0; v < 3; ++v) {
                int jj = j + v - 1; jj = jj < 0 ? 1 : (jj > 255 ? 254 : jj);
                xv[u * 3 + v] = xc[(ii << 8) + jj];
            }
        }
        const float* lwc = &lw[c * 288];
#pragma unroll
        for (int t = 0; t < 9; ++t)
#pragma unroll
            for (int o4 = 0; o4 < 8; ++o4) {
                float4 w4 = *(const float4*)&lwc[t * 32 + o4 * 4];
                acc[o4 * 4 + 0] += xv[t] * w4.x;
                acc[o4 * 4 + 1] += xv[t] * w4.y;
                acc[o4 * 4 + 2] += xv[t] * w4.z;
                acc[o4 * 4 + 3] += xv[t] * w4.w;
            }
    }
    float* yb = y + (size_t)b * 32 * 65536;
#pragma unroll
    for (int o = 0; o < 32; ++o) yb[(size_t)o * 65536 + pix] = acc[o];
}

// ---------------- instance norm, split stats/apply (NCHW, in place) ----------------
// stats: grid (B*C, SPLIT); st[bc] += (sum, sumsq) of HWs contiguous elements
__global__ void in_stats_nchw_kernel(const float* __restrict__ x, float* __restrict__ st,
                                     int HWs, int HW) {
    const float* p = x + (size_t)blockIdx.x * HW + (size_t)blockIdx.y * HWs;
    float s = 0.0f, ss = 0.0f;
    for (int k = threadIdx.x; k < HWs; k += TPB) { float v = p[k]; s += v; ss += v * v; }
#pragma unroll
    for (int o = 32; o > 0; o >>= 1) { s += __shfl_down(s, o); ss += __shfl_down(ss, o); }
    __shared__ float sh[2][4];
    int wv = threadIdx.x >> 6;
    if ((threadIdx.x & 63) == 0) { sh[0][wv] = s; sh[1][wv] = ss; }
    __syncthreads();
    if (threadIdx.x == 0) {
        atomicAdd(&st[blockIdx.x * 2],     sh[0][0] + sh[0][1] + sh[0][2] + sh[0][3]);
        atomicAdd(&st[blockIdx.x * 2 + 1], sh[1][0] + sh[1][1] + sh[1][2] + sh[1][3]);
    }
}
// apply: grid-stride float4; bc = (elem index) >> logHW
__global__ void in_apply_nchw_kernel(float* __restrict__ x, const float* __restrict__ st,
                                     int logHW, float rHW, int n4) {
    int id = blockIdx.x * TPB + threadIdx.x;
    if (id >= n4) return;
    int bc = (int)(((size_t)id << 2) >> logHW);
    float s = st[bc * 2], ss = st[bc * 2 + 1];
    float m = s * rHW;
    float inv = rsqrtf(ss * rHW - m * m + 1e-5f);
    float4* px4 = (float4*)x;
    float4 v = px4[id];
    v.x = (v.x - m) * inv; v.x = v.x >= 0.0f ? v.x : 0.2f * v.x;
    v.y = (v.y - m) * inv; v.y = v.y >= 0.0f ? v.y : 0.2f * v.y;
    v.z = (v.z - m) * inv; v.z = v.z >= 0.0f ? v.z : 0.2f * v.z;
    v.w = (v.w - m) * inv; v.w = v.w >= 0.0f ? v.w : 0.2f * v.w;
    px4[id] = v;
}

// ---------------- strided conv (stride 2, zero pad 1), broadcast weights ----------------
template<int IC, int IH, int IW, int OH, int OW, int OCT>
__global__ __launch_bounds__(256) void conv_s2b_kernel(const float* __restrict__ x,
                                                       const float* __restrict__ w,
                                                       const float* __restrict__ bias,
                                                       float* __restrict__ y, int OC) {
    __shared__ float lw[IC * 9 * OCT];               // [c][t][o]
    int p2 = (blockIdx.x * TPB + threadIdx.x) * 2;
    int i = p2 / OW, j = p2 % OW;
    int ocg = blockIdx.y, b = blockIdx.z;
    for (int k = threadIdx.x; k < IC * 9 * OCT; k += TPB) {
        int o = k & (OCT - 1); int ct = k / OCT; int t = ct % 9; int c = ct / 9;
        lw[k] = w[((size_t)(ocg * OCT + o) * IC + c) * 9 + t];
    }
    __syncthreads();
    float acc0[OCT], acc1[OCT];
#pragma unroll
    for (int o = 0; o < OCT; ++o) { float bv = bias[ocg * OCT + o]; acc0[o] = bv; acc1[o] = bv; }
    const float* xb = x + (size_t)b * IC * IH * IW;
    for (int c = 0; c < IC; ++c) {
        const float* xc = xb + (size_t)c * IH * IW;
        float xr[3][5];
#pragma unroll
        for (int u = 0; u < 3; ++u) {
            int ii = 2 * i + u - 1;
            bool vr = (ii >= 0);
#pragma unroll
            for (int vv = 0; vv < 5; ++vv) {
                int jj = 2 * j + vv - 1;
                xr[u][vv] = (vr && jj >= 0) ? xc[ii * IW + jj] : 0.0f;
            }
        }
        const float* lwc = &lw[c * 9 * OCT];
#pragma unroll
        for (int u = 0; u < 3; ++u)
#pragma unroll
            for (int v = 0; v < 3; ++v) {
                float a = xr[u][v], bx = xr[u][v + 2];
#pragma unroll
                for (int o4 = 0; o4 < OCT / 4; ++o4) {
                    float4 w4 = *(const float4*)&lwc[(u * 3 + v) * OCT + o4 * 4];
                    acc0[o4 * 4 + 0] += a * w4.x;  acc1[o4 * 4 + 0] += bx * w4.x;
                    acc0[o4 * 4 + 1] += a * w4.y;  acc1[o4 * 4 + 1] += bx * w4.y;
                    acc0[o4 * 4 + 2] += a * w4.z;  acc1[o4 * 4 + 2] += bx * w4.z;
                    acc0[o4 * 4 + 3] += a * w4.w;  acc1[o4 * 4 + 3] += bx * w4.w;
                }
            }
    }
    float* yb = y + ((size_t)(b * OC) + ocg * OCT) * (size_t)(OH * OW) + p2;
#pragma unroll
    for (int o = 0; o < OCT; ++o) {
        float2 v2 = make_float2(acc0[o], acc1[o]);
        *(float2*)&yb[(size_t)o * OH * OW] = v2;
    }
}

// ---------------- transpose+split x2: [4,128,64,64] f32 -> [2][4,64,64,128] bf16 ----------------
__global__ void transpose_x2_kernel(const float* __restrict__ x2, unsigned short* __restrict__ x2h) {
    __shared__ __align__(16) unsigned short tileH[64][136];
    __shared__ __align__(16) unsigned short tileL[64][136];
    int h = blockIdx.x, b = blockIdx.y;
    int t = threadIdx.x;
    int px = t & 63, c4 = t >> 6;
    const float* src = x2 + ((size_t)b * 128) * 4096 + h * 64 + px;
#pragma unroll
    for (int k = 0; k < 32; ++k) {
        int c = c4 * 32 + k;
        float v = src[(size_t)c * 4096];
        unsigned short hb = f2bf(v);
        tileH[px][c] = hb;
        tileL[px][c] = f2bf(v - bf2f(hb));
    }
    __syncthreads();
    unsigned short* dh = x2h + ((size_t)(b * 64 + h) * 64) * 128;
#pragma unroll
    for (int k = 0; k < 4; ++k) {
        int chunk = k * 256 + t;
        int p2 = chunk >> 4, c8 = (chunk & 15) << 3;
        *(u16x8_t*)&dh[(size_t)p2 * 128 + c8] = *(const u16x8_t*)&tileH[p2][c8];
        *(u16x8_t*)&dh[2097152 + (size_t)p2 * 128 + c8] = *(const u16x8_t*)&tileL[p2][c8];
    }
}

// ---------------- weight packs ----------------
__global__ void packw_kernel(const float* __restrict__ w3, unsigned short* __restrict__ wph,
                             unsigned short* __restrict__ wpl) {
    int id = blockIdx.x * TPB + threadIdx.x;
    if (id >= 9 * 512 * 256) return;
    int c = id & 255; int to = id >> 8; int o = to & 511; int tt = to >> 9;
    float v = w3[((size_t)o * 256 + c) * 9 + tt];
    unsigned short hb = f2bf(v);
    wph[id] = hb;
    wpl[id] = f2bf(v - bf2f(hb));
}
__global__ void packwt_kernel(const float* __restrict__ wt, unsigned short* __restrict__ wph,
                              unsigned short* __restrict__ wpl) {
    int id = blockIdx.x * TPB + threadIdx.x;
    if (id >= 9 * 256 * 128) return;
    int c = id & 127; int to = id >> 7; int o = to & 255; int tt = to >> 8;
    float v = wt[((size_t)o * 128 + c) * 9 + tt];
    unsigned short hb = f2bf(v);
    wph[id] = hb;
    wpl[id] = f2bf(v - bf2f(hb));
}

// ---------------- convT 128->256 MFMA, all 4 parity classes, fused stats ----------------
__global__ __launch_bounds__(512, 2) void convt_mfma_all_kernel(
    const unsigned short* __restrict__ xh, const unsigned short* __restrict__ wh,
    const unsigned short* __restrict__ wl, const float* __restrict__ bias,
    float* __restrict__ y, float* __restrict__ stats) {
    __shared__ __align__(16) unsigned short ldsW[4][2][64][32];
    __shared__ __align__(16) unsigned short ldsXh[9][66][32];
    __shared__ __align__(16) unsigned short ldsXl[9][66][32];
    __shared__ float sums[64][2];
    int ocg = blockIdx.x, a0 = blockIdx.y * 8;
    int b = blockIdx.z >> 2, cls = blockIdx.z & 3;
    int pi = cls >> 1, pj = cls & 1;
    int nt = (pi + 1) * (pj + 1);
    int tid = threadIdx.x;
    int l = tid & 63, w = tid >> 6;
    int px = l & 15, g = l >> 4;

    f32x4_t acc[4][4];                       // [j (bb frag)][m (oc frag)]
#pragma unroll
    for (int m = 0; m < 4; ++m) {
        float bv = bias[ocg * 64 + 16 * m + px];
#pragma unroll
        for (int j = 0; j < 4; ++j)
#pragma unroll
            for (int r = 0; r < 4; ++r) acc[j][m][r] = bv;
    }
    unsigned short* ldsXhf = &ldsXh[0][0][0];
    unsigned short* ldsXlf = &ldsXl[0][0][0];

    for (int cc = 0; cc < 128; cc += 32) {
        __syncthreads();
        for (int k = 0; k < nt; ++k) {
            int iu = pj ? (k >> 1) : k;
            int iv = pj ? (k & 1) : 0;
            int u = pi ? iu * 2 : 1;
            int v = pj ? iv * 2 : 1;
            int tap = 3 * u + v;
            int gq = tid & 3;
            int o = (tid >> 2) & 63;
            int h = (tid >> 8) & 1;
            const unsigned short* srcp = (h ? wl : wh) +
                ((size_t)tap * 256 + ocg * 64 + o) * 128 + cc + (gq << 3);
            *(u16x8_t*)&ldsW[k][h][o][(gq ^ (o & 3)) << 3] = *(const u16x8_t*)srcp;
        }
        for (int k = 0; k < 5; ++k) {
            int c16 = k * 512 + tid;
            if (c16 < 2376) {
                int gq = c16 & 3;
                int rc = c16 >> 2;
                int row = (rc * 993) >> 16;
                int col = rc - row * 66;
                int gr = a0 + row;
                u16x8_t vh = {}, vl = {};
                if (gr < 64 && col < 64) {
                    size_t sidx = (((size_t)(b * 64 + gr) * 64) + col) * 128 + cc + (gq << 3);
                    vh = *(const u16x8_t*)(xh + sidx);
                    vl = *(const u16x8_t*)(xh + 2097152 + sidx);
                }
                int off = ((rc << 2) | (gq ^ (col & 3))) << 3;
                *(u16x8_t*)(ldsXhf + off) = vh;
                *(u16x8_t*)(ldsXlf + off) = vl;
            }
        }
        __syncthreads();
        for (int k = 0; k < nt; ++k) {
            int dr = pj ? (k >> 1) : k;
            int dc = pj ? (k & 1) : 0;
            bf16x8_t Xh4[4], Xl4[4], Wh4[4], Wl4[4];
#pragma unroll
            for (int j = 0; j < 4; ++j) {
                int col = dc + 16 * j + px;
                int sl = (g ^ (col & 3)) << 3;
                Xh4[j] = *(const bf16x8_t*)&ldsXh[w + dr][col][sl];
                Xl4[j] = *(const bf16x8_t*)&ldsXl[w + dr][col][sl];
            }
            int sA = (g ^ (px & 3)) << 3;
#pragma unroll
            for (int m = 0; m < 4; ++m) {
                Wh4[m] = *(const bf16x8_t*)&ldsW[k][0][16 * m + px][sA];
                Wl4[m] = *(const bf16x8_t*)&ldsW[k][1][16 * m + px][sA];
            }
#pragma unroll
            for (int j = 0; j < 4; ++j)
#pragma unroll
                for (int m = 0; m < 4; ++m) {
                    acc[j][m] = __builtin_amdgcn_mfma_f32_16x16x32_bf16(Xh4[j], Wh4[m], acc[j][m], 0, 0, 0);
                    acc[j][m] = __builtin_amdgcn_mfma_f32_16x16x32_bf16(Xh4[j], Wl4[m], acc[j][m], 0, 0, 0);
                    acc[j][m] = __builtin_amdgcn_mfma_f32_16x16x32_bf16(Xl4[j], Wh4[m], acc[j][m], 0, 0, 0);
                }
        }
    }
    if (tid < 128) (&sums[0][0])[tid] = 0.0f;
    __syncthreads();
    int orow = 2 * (a0 + w) + pi;
    float* yb = y + (((size_t)(b * 128 + orow) * 128)) * 256 + ocg * 64;
#pragma unroll
    for (int m = 0; m < 4; ++m) {
        float sm = 0.0f, ssm = 0.0f;
#pragma unroll
        for (int j = 0; j < 4; ++j)
#pragma unroll
            for (int r = 0; r < 4; ++r) {
                float val = acc[j][m][r];
                sm += val; ssm += val * val;
                int bb = 16 * j + 4 * g + r;
                yb[(size_t)(2 * bb + pj) * 256 + 16 * m + px] = val;
            }
        sm  += __shfl_xor(sm, 16);  sm  += __shfl_xor(sm, 32);
        ssm += __shfl_xor(ssm, 16); ssm += __shfl_xor(ssm, 32);
        if (g == 0) {
            atomicAdd(&sums[16 * m + px][0], sm);
            atomicAdd(&sums[16 * m + px][1], ssm);
        }
    }
    __syncthreads();
    if (tid < 64) {
        atomicAdd(&stats[((size_t)(b * 256) + ocg * 64 + tid) * 2 + 0], sums[tid][0]);
        atomicAdd(&stats[((size_t)(b * 256) + ocg * 64 + tid) * 2 + 1], sums[tid][1]);
    }
}

// ---------------- NHWC instance-norm apply (x3n -> x3h bf16) ----------------
__global__ void in_apply_nhwc_kernel(const float* __restrict__ x, const float* __restrict__ stats,
                                     unsigned short* __restrict__ xhout) {
    int row = blockIdx.x, b = blockIdx.y;
    int c = threadIdx.x;
    float s = stats[(b * 256 + c) * 2], ss = stats[(b * 256 + c) * 2 + 1];
    float m = s * (1.0f / 16384.0f);
    float var = ss * (1.0f / 16384.0f) - m * m;
    float inv = rsqrtf(var + 1e-5f);
    const float* p = x + ((size_t)(b * 128 + row) * 128) * 256 + c;
    unsigned short* q = xhout + ((size_t)(b * 128 + row) * 128) * 256 + c;
    for (int col = 0; col < 128; ++col) {
        float v = (p[(size_t)col * 256] - m) * inv;
        v = v >= 0.0f ? v : 0.2f * v;
        q[(size_t)col * 256] = f2bf(v);
    }
}

// ---------------- conv3 fused: 256->512 MFMA + tanh + segment-sum binning ----------------
// Wave: 64 oc x 2 rows x 64 cols (acc 4x8). Block: 8 waves = 16 rows x 64 cols.
// Staging via global_load_lds (zero staging VGPRs, linear LDS). No codes materialization:
// epilogue bins tanh(acc) into LDS bins[label][oc], flushed to gbins via atomics.
// 1-D grid 512, XCD-aware decode: each XCD gets 2 ocg x 32 tile-instances
// (W slice 2.4MB L2-resident; X tiles shared across the 2 ocg).
__global__ __launch_bounds__(512, 2) void conv3_fused_kernel(
    const unsigned short* __restrict__ xh, const unsigned short* __restrict__ wh,
    const unsigned short* __restrict__ wl, const float* __restrict__ bias,
    const int* __restrict__ lab, float* __restrict__ gbins) {
    __shared__ __align__(16) unsigned short ldsW[9][2][64][32];   // 73,728 B
    __shared__ __align__(16) unsigned short ldsX[18][66][32];     // 76,032 B
    __shared__ float bins[20][64];                                // 5,120 B  (tot 154,880)
    int lin = blockIdx.x;
    int gid = lin & 7;                 // XCD group (round-robin assumption)
    int pos = lin >> 3;                // 0..63
    int ocg = (gid >> 1) * 2 + (pos & 1);
    int inst = (gid & 1) * 32 + (pos >> 1);
    int b = inst >> 4;
    int ty = inst & 15;
    int r0 = (ty >> 1) * 16, c0 = (ty & 1) * 64;
    int tid = threadIdx.x;
    int l = tid & 63, w = tid >> 6;
    int px = l & 15, g = l >> 4;
    int wslot = w << 6;

    for (int k = tid; k < 1280; k += 512) (&bins[0][0])[k] = 0.0f;

    f32x4_t acc[4][8];
#pragma unroll
    for (int m = 0; m < 4; ++m)
#pragma unroll
        for (int r = 0; r < 4; ++r) {
            float bv = bias[(ocg << 6) + 16 * m + 4 * g + r];
#pragma unroll
            for (int n = 0; n < 8; ++n) acc[m][n][r] = bv;
        }

    const unsigned short* xbase = xh + (size_t)b * (128 * 128 * 256);
    unsigned short* ldsWf = &ldsW[0][0][0][0];
    unsigned short* ldsXf = &ldsX[0][0][0];

    for (int cc = 0; cc < 256; cc += 32) {
        __syncthreads();                       // prev chunk's readers done
        // ---- stage W via global_load_lds: 4608 chunks (9 iters x 8 waves x 64 lanes) ----
#pragma unroll
        for (int k = 0; k < 9; ++k) {
            int base = (k << 9) + wslot;       // wave-uniform
            int c16 = base + l;
            int gq = c16 & 3;
            int hto = c16 >> 2;
            int o = hto & 63;
            int th = hto >> 6;
            int h = th & 1, ttap = th >> 1;
            const unsigned short* srcp = (h ? wl : wh) +
                (((size_t)ttap * 512 + (ocg << 6) + o) << 8) + cc + (gq << 3);
            gload16(srcp, ldsWf + ((size_t)base << 3));
        }
        // ---- stage X: 4752 chunks, 10 iters (last partial) ----
#pragma unroll
        for (int k = 0; k < 10; ++k) {
            int base = (k << 9) + wslot;
            int c16 = base + l;
            if (c16 < 4752) {
                int gq = c16 & 3;
                int rc = c16 >> 2;
                int row = (rc * 993) >> 16;    // rc / 66
                int col = rc - row * 66;
                int gi = r0 + row - 1; gi = gi < 0 ? 1 : (gi > 127 ? 126 : gi);
                int gj = c0 + col - 1; gj = gj < 0 ? 1 : (gj > 127 ? 126 : gj);
                const unsigned short* srcp = xbase + ((((size_t)gi << 7) + gj) << 8) + cc + (gq << 3);
                gload16(srcp, ldsXf + ((size_t)base << 3));
            }
        }
        __syncthreads();                       // drains vmcnt (compiler) + barrier
        // ---- compute: per tap, A live across both d; B live 4 frags only ----
#pragma unroll
        for (int u = 0; u < 3; ++u) {
#pragma unroll
            for (int v = 0; v < 3; ++v) {
                int t3 = 3 * u + v;
                bf16x8_t Ah[4], Al[4];
#pragma unroll
                for (int m = 0; m < 4; ++m) {
                    Ah[m] = *(const bf16x8_t*)&ldsW[t3][0][16 * m + px][g << 3];
                    Al[m] = *(const bf16x8_t*)&ldsW[t3][1][16 * m + px][g << 3];
                }
#pragma unroll
                for (int d = 0; d < 2; ++d) {
                    bf16x8_t Bf[4];
#pragma unroll
                    for (int jj = 0; jj < 4; ++jj)
                        Bf[jj] = *(const bf16x8_t*)&ldsX[2 * w + d + u][v + 16 * jj + px][g << 3];
#pragma unroll
                    for (int m = 0; m < 4; ++m)
#pragma unroll
                        for (int jj = 0; jj < 4; ++jj)
                            acc[m][d * 4 + jj] = __builtin_amdgcn_mfma_f32_16x16x32_bf16(
                                Ah[m], Bf[jj], acc[m][d * 4 + jj], 0, 0, 0);
#pragma unroll
                    for (int m = 0; m < 4; ++m)
#pragma unroll
                        for (int jj = 0; jj < 4; ++jj)
                            acc[m][d * 4 + jj] = __builtin_amdgcn_mfma_f32_16x16x32_bf16(
                                Al[m], Bf[jj], acc[m][d * 4 + jj], 0, 0, 0);
                }
            }
        }
    }
    // ---- epilogue: tanh + bin by label (no codes write) ----
    int labs[2][4];
#pragma unroll
    for (int d = 0; d < 2; ++d) {
        const int* lrow = lab + (b << 14) + ((r0 + 2 * w + d) << 7) + c0;
#pragma unroll
        for (int jj = 0; jj < 4; ++jj) labs[d][jj] = lrow[16 * jj + px];
    }
#pragma unroll
    for (int m = 0; m < 4; ++m)
#pragma unroll
        for (int r = 0; r < 4; ++r) {
            int oc = 16 * m + 4 * g + r;
#pragma unroll
            for (int d = 0; d < 2; ++d)
#pragma unroll
                for (int jj = 0; jj < 4; ++jj) {
                    int lb = labs[d][jj];
                    if (lb >= 0) atomicAdd(&bins[lb][oc], tanhf(acc[m][d * 4 + jj][r]));
                }
        }
    __syncthreads();
    for (int k = tid; k < 1280; k += 512) {
        int s = k >> 6, oc = k & 63;
        float v = bins[s][oc];
        if (v != 0.0f)
            atomicAdd(&gbins[(((size_t)b * 20 + s) << 9) + (ocg << 6) + oc], v);
    }
}

// ---------------- labels + counts ----------------
__global__ void label_kernel(const float* __restrict__ seg, const float* __restrict__ fg,
                             int* __restrict__ lab, float* __restrict__ counts) {
    int b = blockIdx.y;
    int pix = blockIdx.x * TPB + threadIdx.x;
    int i = pix >> 7, j = pix & 127;
    int src = ((i * 2) << 8) + (j * 2);
    const float* fgb = fg + (size_t)b * 65536;
    int l = -1;
    if (fgb[src] == 0.0f) {
        const float* sb = seg + (size_t)b * 20 * 65536;
        for (int s = 0; s < 20; ++s)
            if (sb[(size_t)s * 65536 + src] != 0.0f) { l = s; break; }
    }
    lab[b * 16384 + pix] = l;
    __shared__ int bins[20];
    if (threadIdx.x < 20) bins[threadIdx.x] = 0;
    __syncthreads();
    if (l >= 0) atomicAdd(&bins[l], 1);
    __syncthreads();
    if (threadIdx.x < 20 && bins[threadIdx.x] > 0)
        atomicAdd(&counts[b * 20 + threadIdx.x], (float)bins[threadIdx.x]);
}

// ---------------- final divide: out = gbins / counts ----------------
__global__ void segdiv_kernel(const float* __restrict__ gbins, const float* __restrict__ cnt,
                              float* __restrict__ out) {
    int id = blockIdx.x * TPB + threadIdx.x;
    if (id >= 4 * 20 * 512) return;
    int bs = id >> 9;
    float c = cnt[bs];
    out[id] = c > 0.0f ? gbins[id] / c : 0.0f;
}

// ---------------- launch ----------------
extern "C" void kernel_launch(void* const* d_in, const int* in_sizes, int n_in,
                              void* d_out, int out_size, void* d_ws, size_t ws_size,
                              hipStream_t stream) {
    const float* input = (const float*)d_in[0];
    const float* segmap = (const float*)d_in[1];
    const float* fg = (const float*)d_in[2];
    const float* w0 = (const float*)d_in[3];  const float* b0 = (const float*)d_in[4];
    const float* w1 = (const float*)d_in[5];  const float* b1 = (const float*)d_in[6];
    const float* w2 = (const float*)d_in[7];  const float* b2 = (const float*)d_in[8];
    const float* wt = (const float*)d_in[9];  const float* bt = (const float*)d_in[10];
    const float* w3 = (const float*)d_in[11]; const float* b3 = (const float*)d_in[12];

    float* ws = (float*)d_ws;
    float* x0 = ws + OFF_X0;
    float* x1 = ws + OFF_X1;
    float* x2 = ws + OFF_X2;
    unsigned short* x2h = (unsigned short*)(ws + OFF_X2H);
    float* x3n = ws + OFF_X3N;
    unsigned short* x3h = (unsigned short*)(ws + OFF_X3H);
    int*   lab = (int*)(ws + OFF_LAB);
    float* cnt = ws + OFF_CNT;
    float* stats = ws + OFF_STATS;
    float* gbins = ws + OFF_GBINS;
    float* nst0 = ws + OFF_NST0;
    float* nst1 = ws + OFF_NST1;
    float* nst2 = ws + OFF_NST2;
    unsigned short* wph = (unsigned short*)(ws + OFF_WPH);
    unsigned short* wpl = (unsigned short*)(ws + OFF_WPL);
    unsigned short* wtph = (unsigned short*)(ws + OFF_WTPH);
    unsigned short* wtpl = (unsigned short*)(ws + OFF_WTPL);
    float* out = (float*)d_out;

    // zero cnt+stats+gbins+nst in one shot (contiguous region)
    hipMemsetAsync(ws + OFF_CNT, 0, (OFF_NST2 + 1024 - OFF_CNT) * sizeof(float), stream);
    // conv3 weight pack (independent)
    packw_kernel<<<dim3(4608), TPB, 0, stream>>>(w3, wph, wpl);
    // stage 0: conv0 + IN + lrelu -> x0
    conv0b_kernel<<<dim3(256, 4), TPB, 0, stream>>>(input, w0, b0, x0);
    in_stats_nchw_kernel<<<dim3(128, 8), TPB, 0, stream>>>(x0, nst0, 8192, 65536);
    in_apply_nchw_kernel<<<dim3(8192), TPB, 0, stream>>>(x0, nst0, 16, 1.0f / 65536.0f, 2097152);
    // stage 1: s2 conv 32->64 + IN + lrelu -> x1
    conv_s2b_kernel<32, 256, 256, 128, 128, 16><<<dim3(32, 4, 4), TPB, 0, stream>>>(x0, w1, b1, x1, 64);
    in_stats_nchw_kernel<<<dim3(256, 2), TPB, 0, stream>>>(x1, nst1, 8192, 16384);
    in_apply_nchw_kernel<<<dim3(4096), TPB, 0, stream>>>(x1, nst1, 14, 1.0f / 16384.0f, 1048576);
    // stage 2: s2 conv 64->128 + IN + lrelu -> x2
    conv_s2b_kernel<64, 128, 128, 64, 64, 16><<<dim3(8, 8, 4), TPB, 0, stream>>>(x1, w2, b2, x2, 128);
    packwt_kernel<<<dim3(1152), TPB, 0, stream>>>(wt, wtph, wtpl);
    in_stats_nchw_kernel<<<dim3(512, 1), TPB, 0, stream>>>(x2, nst2, 4096, 4096);
    in_apply_nchw_kernel<<<dim3(2048), TPB, 0, stream>>>(x2, nst2, 12, 1.0f / 4096.0f, 524288);
    // stage 3: transpose x2 -> NHWC bf16 hi/lo; convT (all classes, fused stats) -> x3n
    transpose_x2_kernel<<<dim3(64, 4), TPB, 0, stream>>>(x2, x2h);
    convt_mfma_all_kernel<<<dim3(4, 8, 16), 512, 0, stream>>>(x2h, wtph, wtpl, bt, x3n, stats);
    // stage 3.5: NHWC IN + lrelu + bf16 convert -> x3h
    in_apply_nhwc_kernel<<<dim3(128, 4), TPB, 0, stream>>>(x3n, stats, x3h);
    // stage 5a: labels + counts (before conv3)
    label_kernel<<<dim3(64, 4), TPB, 0, stream>>>(segmap, fg, lab, cnt);
    // stage 4+5b: conv3 (bf16 MFMA, split-A) + tanh + fused segment sums
    conv3_fused_kernel<<<dim3(512), 512, 0, stream>>>(x3h, wph, wpl, b3, lab, gbins);
    // stage 5c: divide
    segdiv_kernel<<<dim3(160), TPB, 0, stream>>>(gbins, cnt, out);
}

// Round 6
// 764.259 us; speedup vs baseline: 4.7974x; 1.0666x over previous
//
#include <hip/hip_runtime.h>
#include <hip/hip_bf16.h>
#include <cstddef>

#define TPB 256

typedef float f32x4_t __attribute__((ext_vector_type(4)));
typedef __bf16 bf16x8_t __attribute__((ext_vector_type(8)));
typedef unsigned short u16x8_t __attribute__((ext_vector_type(8)));

// ---------------- workspace layout (float-element offsets) ----------------
// x0:   [4,32,256,256] f32     @ 0           (8,388,608)
// x1:   [4,64,128,128] f32     @ 8,388,608   (4,194,304)   (wtph/wtpl reuse after conv_s2(2))
// x2:   [4,128,64,64] f32      @ 12,582,912  (2,097,152)
// x2h:  [2][4,64,64,128] bf16  @ 14,680,064  (2,097,152)   hi/lo planes
// x3n:  [4,128,128,256] f32    @ 16,777,216  (16,777,216)  ends 33,554,432
// x3h:  [4,128,128,256] bf16   @ 0           (8,388,608)   x0 dead by then
// lab:  [4,128,128] int        @ 33,554,432  (65,536)
// cnt/stats/gbins/nst: one memset region @ 33,619,968 .. 33,664,848
// wph/wpl: conv3 packed weights; wtph/wtpl: convT packed weights (in dead x1)
static const size_t OFF_X0    = 0;
static const size_t OFF_X1    = 8388608;
static const size_t OFF_X2    = 12582912;
static const size_t OFF_X2H   = 14680064;
static const size_t OFF_X3N   = 16777216;
static const size_t OFF_X3H   = 0;
static const size_t OFF_LAB   = 33554432;
static const size_t OFF_CNT   = 33619968;
static const size_t OFF_STATS = 33620048;
static const size_t OFF_GBINS = 33622096;
static const size_t OFF_NST0  = 33663056;
static const size_t OFF_NST1  = 33663312;
static const size_t OFF_NST2  = 33663824;
static const size_t OFF_WPH   = 42008704;
static const size_t OFF_WPL   = 42598528;
static const size_t OFF_WTPH  = 8388608;
static const size_t OFF_WTPL  = 8536064;

__device__ __forceinline__ unsigned short f2bf(float f) {
    unsigned int u = __float_as_uint(f);
    unsigned int r = u + 0x7FFFu + ((u >> 16) & 1u);   // RNE (finite inputs)
    return (unsigned short)(r >> 16);
}
__device__ __forceinline__ float bf2f(unsigned short h) {
    return __uint_as_float(((unsigned int)h) << 16);
}
__device__ __forceinline__ void gload16(const unsigned short* g, unsigned short* l) {
    __builtin_amdgcn_global_load_lds((const __attribute__((address_space(1))) unsigned int*)g,
                                     (__attribute__((address_space(3))) unsigned int*)l, 16, 0, 0);
}

// ---------------- conv0: 3->32, 256x256, reflect pad 1 ----------------
__global__ __launch_bounds__(256) void conv0b_kernel(const float* __restrict__ x,
                                                     const float* __restrict__ w,
                                                     const float* __restrict__ bias,
                                                     float* __restrict__ y) {
    __shared__ float lw[3 * 9 * 32];                 // [c][t][o]
    int pix = blockIdx.x * TPB + threadIdx.x;
    int i = pix >> 8, j = pix & 255;
    int b = blockIdx.y;
    for (int k = threadIdx.x; k < 864; k += TPB) {
        int o = k & 31; int ct = k >> 5; int t = ct % 9; int c = ct / 9;
        lw[k] = w[((size_t)o * 3 + c) * 9 + t];
    }
    __syncthreads();
    float acc[32];
#pragma unroll
    for (int o = 0; o < 32; ++o) acc[o] = bias[o];
    const float* xb = x + (size_t)b * 3 * 65536;
    for (int c = 0; c < 3; ++c) {
        const float* xc = xb + c * 65536;
        float xv[9];
#pragma unroll
        for (int u = 0; u < 3; ++u) {
            int ii = i + u - 1; ii = ii < 0 ? 1 : (ii > 255 ? 254 : ii);
#pragma unroll
            for (int v = 0; v < 3; ++v) {
                int jj = j + v - 1; jj = jj < 0 ? 1 : (jj > 255 ? 254 : jj);
                xv[u * 3 + v] = xc[(ii << 8) + jj];
            }
        }
        const float* lwc = &lw[c * 288];
#pragma unroll
        for (int t = 0; t < 9; ++t)
#pragma unroll
            for (int o4 = 0; o4 < 8; ++o4) {
                float4 w4 = *(const float4*)&lwc[t * 32 + o4 * 4];
                acc[o4 * 4 + 0] += xv[t] * w4.x;
                acc[o4 * 4 + 1] += xv[t] * w4.y;
                acc[o4 * 4 + 2] += xv[t] * w4.z;
                acc[o4 * 4 + 3] += xv[t] * w4.w;
            }
    }
    float* yb = y + (size_t)b * 32 * 65536;
#pragma unroll
    for (int o = 0; o < 32; ++o) yb[(size_t)o * 65536 + pix] = acc[o];
}

// ---------------- instance norm, split stats/apply (NCHW, in place) ----------------
__global__ void in_stats_nchw_kernel(const float* __restrict__ x, float* __restrict__ st,
                                     int HWs, int HW) {
    const float* p = x + (size_t)blockIdx.x * HW + (size_t)blockIdx.y * HWs;
    float s = 0.0f, ss = 0.0f;
    for (int k = threadIdx.x; k < HWs; k += TPB) { float v = p[k]; s += v; ss += v * v; }
#pragma unroll
    for (int o = 32; o > 0; o >>= 1) { s += __shfl_down(s, o); ss += __shfl_down(ss, o); }
    __shared__ float sh[2][4];
    int wv = threadIdx.x >> 6;
    if ((threadIdx.x & 63) == 0) { sh[0][wv] = s; sh[1][wv] = ss; }
    __syncthreads();
    if (threadIdx.x == 0) {
        atomicAdd(&st[blockIdx.x * 2],     sh[0][0] + sh[0][1] + sh[0][2] + sh[0][3]);
        atomicAdd(&st[blockIdx.x * 2 + 1], sh[1][0] + sh[1][1] + sh[1][2] + sh[1][3]);
    }
}
__global__ void in_apply_nchw_kernel(float* __restrict__ x, const float* __restrict__ st,
                                     int logHW, float rHW, int n4) {
    int id = blockIdx.x * TPB + threadIdx.x;
    if (id >= n4) return;
    int bc = (int)(((size_t)id << 2) >> logHW);
    float s = st[bc * 2], ss = st[bc * 2 + 1];
    float m = s * rHW;
    float inv = rsqrtf(ss * rHW - m * m + 1e-5f);
    float4* px4 = (float4*)x;
    float4 v = px4[id];
    v.x = (v.x - m) * inv; v.x = v.x >= 0.0f ? v.x : 0.2f * v.x;
    v.y = (v.y - m) * inv; v.y = v.y >= 0.0f ? v.y : 0.2f * v.y;
    v.z = (v.z - m) * inv; v.z = v.z >= 0.0f ? v.z : 0.2f * v.z;
    v.w = (v.w - m) * inv; v.w = v.w >= 0.0f ? v.w : 0.2f * v.w;
    px4[id] = v;
}

// ---------------- strided conv (stride 2, zero pad 1), broadcast weights ----------------
template<int IC, int IH, int IW, int OH, int OW, int OCT>
__global__ __launch_bounds__(256) void conv_s2b_kernel(const float* __restrict__ x,
                                                       const float* __restrict__ w,
                                                       const float* __restrict__ bias,
                                                       float* __restrict__ y, int OC) {
    __shared__ float lw[IC * 9 * OCT];               // [c][t][o]
    int p2 = (blockIdx.x * TPB + threadIdx.x) * 2;
    int i = p2 / OW, j = p2 % OW;
    int ocg = blockIdx.y, b = blockIdx.z;
    for (int k = threadIdx.x; k < IC * 9 * OCT; k += TPB) {
        int o = k & (OCT - 1); int ct = k / OCT; int t = ct % 9; int c = ct / 9;
        lw[k] = w[((size_t)(ocg * OCT + o) * IC + c) * 9 + t];
    }
    __syncthreads();
    float acc0[OCT], acc1[OCT];
#pragma unroll
    for (int o = 0; o < OCT; ++o) { float bv = bias[ocg * OCT + o]; acc0[o] = bv; acc1[o] = bv; }
    const float* xb = x + (size_t)b * IC * IH * IW;
    for (int c = 0; c < IC; ++c) {
        const float* xc = xb + (size_t)c * IH * IW;
        float xr[3][5];
#pragma unroll
        for (int u = 0; u < 3; ++u) {
            int ii = 2 * i + u - 1;
            bool vr = (ii >= 0);
#pragma unroll
            for (int vv = 0; vv < 5; ++vv) {
                int jj = 2 * j + vv - 1;
                xr[u][vv] = (vr && jj >= 0) ? xc[ii * IW + jj] : 0.0f;
            }
        }
        const float* lwc = &lw[c * 9 * OCT];
#pragma unroll
        for (int u = 0; u < 3; ++u)
#pragma unroll
            for (int v = 0; v < 3; ++v) {
                float a = xr[u][v], bx = xr[u][v + 2];
#pragma unroll
                for (int o4 = 0; o4 < OCT / 4; ++o4) {
                    float4 w4 = *(const float4*)&lwc[(u * 3 + v) * OCT + o4 * 4];
                    acc0[o4 * 4 + 0] += a * w4.x;  acc1[o4 * 4 + 0] += bx * w4.x;
                    acc0[o4 * 4 + 1] += a * w4.y;  acc1[o4 * 4 + 1] += bx * w4.y;
                    acc0[o4 * 4 + 2] += a * w4.z;  acc1[o4 * 4 + 2] += bx * w4.z;
                    acc0[o4 * 4 + 3] += a * w4.w;  acc1[o4 * 4 + 3] += bx * w4.w;
                }
            }
    }
    float* yb = y + ((size_t)(b * OC) + ocg * OCT) * (size_t)(OH * OW) + p2;
#pragma unroll
    for (int o = 0; o < OCT; ++o) {
        float2 v2 = make_float2(acc0[o], acc1[o]);
        *(float2*)&yb[(size_t)o * OH * OW] = v2;
    }
}

// ---------------- transpose+split x2: [4,128,64,64] f32 -> [2][4,64,64,128] bf16 ----------------
__global__ void transpose_x2_kernel(const float* __restrict__ x2, unsigned short* __restrict__ x2h) {
    __shared__ __align__(16) unsigned short tileH[64][136];
    __shared__ __align__(16) unsigned short tileL[64][136];
    int h = blockIdx.x, b = blockIdx.y;
    int t = threadIdx.x;
    int px = t & 63, c4 = t >> 6;
    const float* src = x2 + ((size_t)b * 128) * 4096 + h * 64 + px;
#pragma unroll
    for (int k = 0; k < 32; ++k) {
        int c = c4 * 32 + k;
        float v = src[(size_t)c * 4096];
        unsigned short hb = f2bf(v);
        tileH[px][c] = hb;
        tileL[px][c] = f2bf(v - bf2f(hb));
    }
    __syncthreads();
    unsigned short* dh = x2h + ((size_t)(b * 64 + h) * 64) * 128;
#pragma unroll
    for (int k = 0; k < 4; ++k) {
        int chunk = k * 256 + t;
        int p2 = chunk >> 4, c8 = (chunk & 15) << 3;
        *(u16x8_t*)&dh[(size_t)p2 * 128 + c8] = *(const u16x8_t*)&tileH[p2][c8];
        *(u16x8_t*)&dh[2097152 + (size_t)p2 * 128 + c8] = *(const u16x8_t*)&tileL[p2][c8];
    }
}

// ---------------- weight packs ----------------
__global__ void packw_kernel(const float* __restrict__ w3, unsigned short* __restrict__ wph,
                             unsigned short* __restrict__ wpl) {
    int id = blockIdx.x * TPB + threadIdx.x;
    if (id >= 9 * 512 * 256) return;
    int c = id & 255; int to = id >> 8; int o = to & 511; int tt = to >> 9;
    float v = w3[((size_t)o * 256 + c) * 9 + tt];
    unsigned short hb = f2bf(v);
    wph[id] = hb;
    wpl[id] = f2bf(v - bf2f(hb));
}
__global__ void packwt_kernel(const float* __restrict__ wt, unsigned short* __restrict__ wph,
                              unsigned short* __restrict__ wpl) {
    int id = blockIdx.x * TPB + threadIdx.x;
    if (id >= 9 * 256 * 128) return;
    int c = id & 127; int to = id >> 7; int o = to & 255; int tt = to >> 8;
    float v = wt[((size_t)o * 128 + c) * 9 + tt];
    unsigned short hb = f2bf(v);
    wph[id] = hb;
    wpl[id] = f2bf(v - bf2f(hb));
}

// ---------------- convT 128->256 MFMA, all 4 parity classes, fused stats ----------------
// NOTE: plain __launch_bounds__(512): min-waves arg proved to cap VGPR at 128 (spill).
__global__ __launch_bounds__(512) void convt_mfma_all_kernel(
    const unsigned short* __restrict__ xh, const unsigned short* __restrict__ wh,
    const unsigned short* __restrict__ wl, const float* __restrict__ bias,
    float* __restrict__ y, float* __restrict__ stats) {
    __shared__ __align__(16) unsigned short ldsW[4][2][64][32];
    __shared__ __align__(16) unsigned short ldsXh[9][66][32];
    __shared__ __align__(16) unsigned short ldsXl[9][66][32];
    __shared__ float sums[64][2];
    int ocg = blockIdx.x, a0 = blockIdx.y * 8;
    int b = blockIdx.z >> 2, cls = blockIdx.z & 3;
    int pi = cls >> 1, pj = cls & 1;
    int nt = (pi + 1) * (pj + 1);
    int tid = threadIdx.x;
    int l = tid & 63, w = tid >> 6;
    int px = l & 15, g = l >> 4;

    f32x4_t acc[4][4];                       // [j (bb frag)][m (oc frag)]
#pragma unroll
    for (int m = 0; m < 4; ++m) {
        float bv = bias[ocg * 64 + 16 * m + px];
#pragma unroll
        for (int j = 0; j < 4; ++j)
#pragma unroll
            for (int r = 0; r < 4; ++r) acc[j][m][r] = bv;
    }
    unsigned short* ldsXhf = &ldsXh[0][0][0];
    unsigned short* ldsXlf = &ldsXl[0][0][0];

    for (int cc = 0; cc < 128; cc += 32) {
        __syncthreads();
        for (int k = 0; k < nt; ++k) {
            int iu = pj ? (k >> 1) : k;
            int iv = pj ? (k & 1) : 0;
            int u = pi ? iu * 2 : 1;
            int v = pj ? iv * 2 : 1;
            int tap = 3 * u + v;
            int gq = tid & 3;
            int o = (tid >> 2) & 63;
            int h = (tid >> 8) & 1;
            const unsigned short* srcp = (h ? wl : wh) +
                ((size_t)tap * 256 + ocg * 64 + o) * 128 + cc + (gq << 3);
            *(u16x8_t*)&ldsW[k][h][o][(gq ^ (o & 3)) << 3] = *(const u16x8_t*)srcp;
        }
        for (int k = 0; k < 5; ++k) {
            int c16 = k * 512 + tid;
            if (c16 < 2376) {
                int gq = c16 & 3;
                int rc = c16 >> 2;
                int row = (rc * 993) >> 16;
                int col = rc - row * 66;
                int gr = a0 + row;
                u16x8_t vh = {}, vl = {};
                if (gr < 64 && col < 64) {
                    size_t sidx = (((size_t)(b * 64 + gr) * 64) + col) * 128 + cc + (gq << 3);
                    vh = *(const u16x8_t*)(xh + sidx);
                    vl = *(const u16x8_t*)(xh + 2097152 + sidx);
                }
                int off = ((rc << 2) | (gq ^ (col & 3))) << 3;
                *(u16x8_t*)(ldsXhf + off) = vh;
                *(u16x8_t*)(ldsXlf + off) = vl;
            }
        }
        __syncthreads();
        for (int k = 0; k < nt; ++k) {
            int dr = pj ? (k >> 1) : k;
            int dc = pj ? (k & 1) : 0;
            bf16x8_t Xh4[4], Xl4[4], Wh4[4], Wl4[4];
#pragma unroll
            for (int j = 0; j < 4; ++j) {
                int col = dc + 16 * j + px;
                int sl = (g ^ (col & 3)) << 3;
                Xh4[j] = *(const bf16x8_t*)&ldsXh[w + dr][col][sl];
                Xl4[j] = *(const bf16x8_t*)&ldsXl[w + dr][col][sl];
            }
            int sA = (g ^ (px & 3)) << 3;
#pragma unroll
            for (int m = 0; m < 4; ++m) {
                Wh4[m] = *(const bf16x8_t*)&ldsW[k][0][16 * m + px][sA];
                Wl4[m] = *(const bf16x8_t*)&ldsW[k][1][16 * m + px][sA];
            }
#pragma unroll
            for (int j = 0; j < 4; ++j)
#pragma unroll
                for (int m = 0; m < 4; ++m) {
                    acc[j][m] = __builtin_amdgcn_mfma_f32_16x16x32_bf16(Xh4[j], Wh4[m], acc[j][m], 0, 0, 0);
                    acc[j][m] = __builtin_amdgcn_mfma_f32_16x16x32_bf16(Xh4[j], Wl4[m], acc[j][m], 0, 0, 0);
                    acc[j][m] = __builtin_amdgcn_mfma_f32_16x16x32_bf16(Xl4[j], Wh4[m], acc[j][m], 0, 0, 0);
                }
        }
    }
    if (tid < 128) (&sums[0][0])[tid] = 0.0f;
    __syncthreads();
    int orow = 2 * (a0 + w) + pi;
    float* yb = y + (((size_t)(b * 128 + orow) * 128)) * 256 + ocg * 64;
#pragma unroll
    for (int m = 0; m < 4; ++m) {
        float sm = 0.0f, ssm = 0.0f;
#pragma unroll
        for (int j = 0; j < 4; ++j)
#pragma unroll
            for (int r = 0; r < 4; ++r) {
                float val = acc[j][m][r];
                sm += val; ssm += val * val;
                int bb = 16 * j + 4 * g + r;
                yb[(size_t)(2 * bb + pj) * 256 + 16 * m + px] = val;
            }
        sm  += __shfl_xor(sm, 16);  sm  += __shfl_xor(sm, 32);
        ssm += __shfl_xor(ssm, 16); ssm += __shfl_xor(ssm, 32);
        if (g == 0) {
            atomicAdd(&sums[16 * m + px][0], sm);
            atomicAdd(&sums[16 * m + px][1], ssm);
        }
    }
    __syncthreads();
    if (tid < 64) {
        atomicAdd(&stats[((size_t)(b * 256) + ocg * 64 + tid) * 2 + 0], sums[tid][0]);
        atomicAdd(&stats[((size_t)(b * 256) + ocg * 64 + tid) * 2 + 1], sums[tid][1]);
    }
}

// ---------------- NHWC instance-norm apply (x3n -> x3h bf16), vectorized ----------------
// grid (128 rows, 4 b), block 256. Per thread-iter: 8 consecutive channels of one pixel.
__global__ void in_apply_nhwc_kernel(const float* __restrict__ x, const float* __restrict__ stats,
                                     unsigned short* __restrict__ xhout) {
    __shared__ float sm[256], sinv[256];
    int row = blockIdx.x, b = blockIdx.y;
    int tid = threadIdx.x;
    {
        float s = stats[(b * 256 + tid) * 2], ss = stats[(b * 256 + tid) * 2 + 1];
        float mm = s * (1.0f / 16384.0f);
        sm[tid] = mm;
        sinv[tid] = rsqrtf(ss * (1.0f / 16384.0f) - mm * mm + 1e-5f);
    }
    __syncthreads();
    const float* xr = x + ((size_t)(b * 128 + row) * 128) * 256;
    unsigned short* qr = xhout + ((size_t)(b * 128 + row) * 128) * 256;
    for (int idx = tid; idx < 128 * 32; idx += TPB) {
        int col = idx >> 5, c8 = (idx & 31) << 3;
        const float* p = xr + col * 256 + c8;
        float4 v0 = *(const float4*)p;
        float4 v1 = *(const float4*)(p + 4);
        float vs[8] = {v0.x, v0.y, v0.z, v0.w, v1.x, v1.y, v1.z, v1.w};
        u16x8_t o;
#pragma unroll
        for (int q = 0; q < 8; ++q) {
            int c = c8 + q;
            float f = (vs[q] - sm[c]) * sinv[c];
            f = f >= 0.0f ? f : 0.2f * f;
            o[q] = f2bf(f);
        }
        *(u16x8_t*)&qr[col * 256 + c8] = o;
    }
}

// ---------------- conv3 fused: 256->512 MFMA + tanh + segment-sum binning ----------------
// Wave: 64 oc x 2 rows x 64 cols (acc 4x8). Block: 8 waves = 16 rows x 64 cols.
// Staging via global_load_lds (zero staging VGPRs). Epilogue bins tanh(acc) into
// LDS bins[label][oc] -> gbins atomics; codes never materialized.
// Plain __launch_bounds__(512): the (512,2) form capped VGPR at 128 -> 331MB spill (r4/r5).
__global__ __launch_bounds__(512) void conv3_fused_kernel(
    const unsigned short* __restrict__ xh, const unsigned short* __restrict__ wh,
    const unsigned short* __restrict__ wl, const float* __restrict__ bias,
    const int* __restrict__ lab, float* __restrict__ gbins) {
    __shared__ __align__(16) unsigned short ldsW[9][2][64][32];   // 73,728 B
    __shared__ __align__(16) unsigned short ldsX[18][66][32];     // 76,032 B
    __shared__ float bins[20][64];                                // 5,120 B  (tot 154,880)
    int lin = blockIdx.x;
    int gid = lin & 7;                 // XCD group (round-robin assumption)
    int pos = lin >> 3;                // 0..63
    int ocg = (gid >> 1) * 2 + (pos & 1);
    int inst = (gid & 1) * 32 + (pos >> 1);
    int b = inst >> 4;
    int ty = inst & 15;
    int r0 = (ty >> 1) * 16, c0 = (ty & 1) * 64;
    int tid = threadIdx.x;
    int l = tid & 63, w = tid >> 6;
    int px = l & 15, g = l >> 4;
    int wslot = w << 6;

    for (int k = tid; k < 1280; k += 512) (&bins[0][0])[k] = 0.0f;

    f32x4_t acc[4][8];
#pragma unroll
    for (int m = 0; m < 4; ++m)
#pragma unroll
        for (int r = 0; r < 4; ++r) {
            float bv = bias[(ocg << 6) + 16 * m + 4 * g + r];
#pragma unroll
            for (int n = 0; n < 8; ++n) acc[m][n][r] = bv;
        }

    const unsigned short* xbase = xh + (size_t)b * (128 * 128 * 256);
    unsigned short* ldsWf = &ldsW[0][0][0][0];
    unsigned short* ldsXf = &ldsX[0][0][0];

    for (int cc = 0; cc < 256; cc += 32) {
        __syncthreads();                       // prev chunk's readers done
        // ---- stage W via global_load_lds: 4608 chunks (9 iters) ----
#pragma unroll
        for (int k = 0; k < 9; ++k) {
            int base = (k << 9) + wslot;       // wave-uniform
            int c16 = base + l;
            int gq = c16 & 3;
            int hto = c16 >> 2;
            int o = hto & 63;
            int th = hto >> 6;
            int h = th & 1, ttap = th >> 1;
            const unsigned short* srcp = (h ? wl : wh) +
                (((size_t)ttap * 512 + (ocg << 6) + o) << 8) + cc + (gq << 3);
            gload16(srcp, ldsWf + ((size_t)base << 3));
        }
        // ---- stage X: 4752 chunks, 10 iters (last partial) ----
#pragma unroll
        for (int k = 0; k < 10; ++k) {
            int base = (k << 9) + wslot;
            int c16 = base + l;
            if (c16 < 4752) {
                int gq = c16 & 3;
                int rc = c16 >> 2;
                int row = (rc * 993) >> 16;    // rc / 66
                int col = rc - row * 66;
                int gi = r0 + row - 1; gi = gi < 0 ? 1 : (gi > 127 ? 126 : gi);
                int gj = c0 + col - 1; gj = gj < 0 ? 1 : (gj > 127 ? 126 : gj);
                const unsigned short* srcp = xbase + ((((size_t)gi << 7) + gj) << 8) + cc + (gq << 3);
                gload16(srcp, ldsXf + ((size_t)base << 3));
            }
        }
        __syncthreads();                       // drains vmcnt (compiler) + barrier
        // ---- compute ----
#pragma unroll
        for (int u = 0; u < 3; ++u) {
#pragma unroll
            for (int v = 0; v < 3; ++v) {
                int t3 = 3 * u + v;
                bf16x8_t Ah[4], Al[4];
#pragma unroll
                for (int m = 0; m < 4; ++m) {
                    Ah[m] = *(const bf16x8_t*)&ldsW[t3][0][16 * m + px][g << 3];
                    Al[m] = *(const bf16x8_t*)&ldsW[t3][1][16 * m + px][g << 3];
                }
#pragma unroll
                for (int d = 0; d < 2; ++d) {
                    bf16x8_t Bf[4];
#pragma unroll
                    for (int jj = 0; jj < 4; ++jj)
                        Bf[jj] = *(const bf16x8_t*)&ldsX[2 * w + d + u][v + 16 * jj + px][g << 3];
#pragma unroll
                    for (int m = 0; m < 4; ++m)
#pragma unroll
                        for (int jj = 0; jj < 4; ++jj)
                            acc[m][d * 4 + jj] = __builtin_amdgcn_mfma_f32_16x16x32_bf16(
                                Ah[m], Bf[jj], acc[m][d * 4 + jj], 0, 0, 0);
#pragma unroll
                    for (int m = 0; m < 4; ++m)
#pragma unroll
                        for (int jj = 0; jj < 4; ++jj)
                            acc[m][d * 4 + jj] = __builtin_amdgcn_mfma_f32_16x16x32_bf16(
                                Al[m], Bf[jj], acc[m][d * 4 + jj], 0, 0, 0);
                }
            }
        }
    }
    // ---- epilogue: tanh + bin by label ----
    int labs[2][4];
#pragma unroll
    for (int d = 0; d < 2; ++d) {
        const int* lrow = lab + (b << 14) + ((r0 + 2 * w + d) << 7) + c0;
#pragma unroll
        for (int jj = 0; jj < 4; ++jj) labs[d][jj] = lrow[16 * jj + px];
    }
#pragma unroll
    for (int m = 0; m < 4; ++m)
#pragma unroll
        for (int r = 0; r < 4; ++r) {
            int oc = 16 * m + 4 * g + r;
#pragma unroll
            for (int d = 0; d < 2; ++d)
#pragma unroll
                for (int jj = 0; jj < 4; ++jj) {
                    int lb = labs[d][jj];
                    if (lb >= 0) atomicAdd(&bins[lb][oc], tanhf(acc[m][d * 4 + jj][r]));
                }
        }
    __syncthreads();
    for (int k = tid; k < 1280; k += 512) {
        int s = k >> 6, oc = k & 63;
        float v = bins[s][oc];
        if (v != 0.0f)
            atomicAdd(&gbins[(((size_t)b * 20 + s) << 9) + (ocg << 6) + oc], v);
    }
}

// ---------------- labels + counts ----------------
__global__ void label_kernel(const float* __restrict__ seg, const float* __restrict__ fg,
                             int* __restrict__ lab, float* __restrict__ counts) {
    int b = blockIdx.y;
    int pix = blockIdx.x * TPB + threadIdx.x;
    int i = pix >> 7, j = pix & 127;
    int src = ((i * 2) << 8) + (j * 2);
    const float* fgb = fg + (size_t)b * 65536;
    int l = -1;
    if (fgb[src] == 0.0f) {
        const float* sb = seg + (size_t)b * 20 * 65536;
        for (int s = 0; s < 20; ++s)
            if (sb[(size_t)s * 65536 + src] != 0.0f) { l = s; break; }
    }
    lab[b * 16384 + pix] = l;
    __shared__ int bins[20];
    if (threadIdx.x < 20) bins[threadIdx.x] = 0;
    __syncthreads();
    if (l >= 0) atomicAdd(&bins[l], 1);
    __syncthreads();
    if (threadIdx.x < 20 && bins[threadIdx.x] > 0)
        atomicAdd(&counts[b * 20 + threadIdx.x], (float)bins[threadIdx.x]);
}

// ---------------- final divide: out = gbins / counts ----------------
__global__ void segdiv_kernel(const float* __restrict__ gbins, const float* __restrict__ cnt,
                              float* __restrict__ out) {
    int id = blockIdx.x * TPB + threadIdx.x;
    if (id >= 4 * 20 * 512) return;
    int bs = id >> 9;
    float c = cnt[bs];
    out[id] = c > 0.0f ? gbins[id] / c : 0.0f;
}

// ---------------- launch ----------------
extern "C" void kernel_launch(void* const* d_in, const int* in_sizes, int n_in,
                              void* d_out, int out_size, void* d_ws, size_t ws_size,
                              hipStream_t stream) {
    const float* input = (const float*)d_in[0];
    const float* segmap = (const float*)d_in[1];
    const float* fg = (const float*)d_in[2];
    const float* w0 = (const float*)d_in[3];  const float* b0 = (const float*)d_in[4];
    const float* w1 = (const float*)d_in[5];  const float* b1 = (const float*)d_in[6];
    const float* w2 = (const float*)d_in[7];  const float* b2 = (const float*)d_in[8];
    const float* wt = (const float*)d_in[9];  const float* bt = (const float*)d_in[10];
    const float* w3 = (const float*)d_in[11]; const float* b3 = (const float*)d_in[12];

    float* ws = (float*)d_ws;
    float* x0 = ws + OFF_X0;
    float* x1 = ws + OFF_X1;
    float* x2 = ws + OFF_X2;
    unsigned short* x2h = (unsigned short*)(ws + OFF_X2H);
    float* x3n = ws + OFF_X3N;
    unsigned short* x3h = (unsigned short*)(ws + OFF_X3H);
    int*   lab = (int*)(ws + OFF_LAB);
    float* cnt = ws + OFF_CNT;
    float* stats = ws + OFF_STATS;
    float* gbins = ws + OFF_GBINS;
    float* nst0 = ws + OFF_NST0;
    float* nst1 = ws + OFF_NST1;
    float* nst2 = ws + OFF_NST2;
    unsigned short* wph = (unsigned short*)(ws + OFF_WPH);
    unsigned short* wpl = (unsigned short*)(ws + OFF_WPL);
    unsigned short* wtph = (unsigned short*)(ws + OFF_WTPH);
    unsigned short* wtpl = (unsigned short*)(ws + OFF_WTPL);
    float* out = (float*)d_out;

    // zero cnt+stats+gbins+nst in one shot (contiguous region)
    hipMemsetAsync(ws + OFF_CNT, 0, (OFF_NST2 + 1024 - OFF_CNT) * sizeof(float), stream);
    // conv3 weight pack (independent)
    packw_kernel<<<dim3(4608), TPB, 0, stream>>>(w3, wph, wpl);
    // stage 0: conv0 + IN + lrelu -> x0
    conv0b_kernel<<<dim3(256, 4), TPB, 0, stream>>>(input, w0, b0, x0);
    in_stats_nchw_kernel<<<dim3(128, 8), TPB, 0, stream>>>(x0, nst0, 8192, 65536);
    in_apply_nchw_kernel<<<dim3(8192), TPB, 0, stream>>>(x0, nst0, 16, 1.0f / 65536.0f, 2097152);
    // stage 1: s2 conv 32->64 + IN + lrelu -> x1
    conv_s2b_kernel<32, 256, 256, 128, 128, 16><<<dim3(32, 4, 4), TPB, 0, stream>>>(x0, w1, b1, x1, 64);
    in_stats_nchw_kernel<<<dim3(256, 2), TPB, 0, stream>>>(x1, nst1, 8192, 16384);
    in_apply_nchw_kernel<<<dim3(4096), TPB, 0, stream>>>(x1, nst1, 14, 1.0f / 16384.0f, 1048576);
    // stage 2: s2 conv 64->128 + IN + lrelu -> x2
    conv_s2b_kernel<64, 128, 128, 64, 64, 16><<<dim3(8, 8, 4), TPB, 0, stream>>>(x1, w2, b2, x2, 128);
    packwt_kernel<<<dim3(1152), TPB, 0, stream>>>(wt, wtph, wtpl);
    in_stats_nchw_kernel<<<dim3(512, 1), TPB, 0, stream>>>(x2, nst2, 4096, 4096);
    in_apply_nchw_kernel<<<dim3(2048), TPB, 0, stream>>>(x2, nst2, 12, 1.0f / 4096.0f, 524288);
    // stage 3: transpose x2 -> NHWC bf16 hi/lo; convT (all classes, fused stats) -> x3n
    transpose_x2_kernel<<<dim3(64, 4), TPB, 0, stream>>>(x2, x2h);
    convt_mfma_all_kernel<<<dim3(4, 8, 16), 512, 0, stream>>>(x2h, wtph, wtpl, bt, x3n, stats);
    // stage 3.5: NHWC IN + lrelu + bf16 convert -> x3h
    in_apply_nhwc_kernel<<<dim3(128, 4), TPB, 0, stream>>>(x3n, stats, x3h);
    // stage 5a: labels + counts (before conv3)
    label_kernel<<<dim3(64, 4), TPB, 0, stream>>>(segmap, fg, lab, cnt);
    // stage 4+5b: conv3 (bf16 MFMA, split-A) + tanh + fused segment sums
    conv3_fused_kernel<<<dim3(512), 512, 0, stream>>>(x3h, wph, wpl, b3, lab, gbins);
    // stage 5c: divide
    segdiv_kernel<<<dim3(160), TPB, 0, stream>>>(gbins, cnt, out);
}